// Round 3
// baseline (5750.948 us; speedup 1.0000x reference)
//
#include <hip/hip_runtime.h>
#include <hip/hip_bf16.h>

// Problem constants (from reference):
#define NN 50000   // nodes
#define FF 128     // in channels
#define NH 4       // heads
#define CH 32      // channels/head
#define HC 128     // NH*CH
#define NE 800000  // edges
#define NR 8       // relations
#define DEDIM 64   // edge emb dim

typedef __hip_bfloat16 bf16;

// ---- helpers ----------------------------------------------------------------
__device__ __forceinline__ float bflo(unsigned u) { return __uint_as_float(u << 16); }
__device__ __forceinline__ float bfhi(unsigned u) { return __uint_as_float(u & 0xFFFF0000u); }

__device__ __forceinline__ unsigned short f2bf(float f) {
  unsigned u = __float_as_uint(f);
  unsigned r = (u + 0x7FFFu + ((u >> 16) & 1u)) >> 16;  // round-nearest-even
  return (unsigned short)r;
}
__device__ __forceinline__ unsigned pack2bf(float lo, float hi) {
  return (unsigned)f2bf(lo) | ((unsigned)f2bf(hi) << 16);
}

// dtype-dispatched scalar load of a "float-like" input
template <int ISBF>
__device__ __forceinline__ float ldf(const void* p, size_t i) {
  if (ISBF) return __bfloat162float(((const bf16*)p)[i]);
  return ((const float*)p)[i];
}

// index load robust to int64/int32 (explicit branch: never speculate the
// wide-load path on narrow data)
__device__ __forceinline__ int idx_at(const void* p, long long i, int is64) {
  if (is64) { long long v = ((const long long*)p)[i]; return (int)v; }
  return ((const int*)p)[i];
}

// ---- kernels ----------------------------------------------------------------

// flag[0]: 1 if edge_index is int64 (hi32 of first 128 pairs all zero)
// flag[1]: 1 if x is bf16 (low-16 of first 128 words all have sane bf16 exp)
__global__ __launch_bounds__(128) void k_detect(const int* __restrict__ eidx32,
                                                const unsigned* __restrict__ xw,
                                                int* __restrict__ flag) {
  __shared__ int nzIdx, badBf;
  if (threadIdx.x == 0) { nzIdx = 0; badBf = 0; }
  __syncthreads();
  if (eidx32[2 * threadIdx.x + 1] != 0) atomicAdd(&nzIdx, 1);
  unsigned e = (xw[threadIdx.x] >> 7) & 0xFFu;  // exponent of low-half bf16
  if (e < 90u || e > 140u) atomicAdd(&badBf, 1);
  __syncthreads();
  if (threadIdx.x == 0) { flag[0] = (nzIdx == 0); flag[1] = (badBf == 0); }
}

// denom = 0
__global__ __launch_bounds__(256) void k_init(float* __restrict__ denom) {
  int i = blockIdx.x * 256 + threadIdx.x;
  if (i < NN * NH) denom[i] = 0.f;
}

// ee[r][j] = sum_d edge_emb[r][d] * We[d][j]   (8x128 fp32, one block)
__global__ __launch_bounds__(256) void k_ee(const void* __restrict__ emb,
                                            const void* __restrict__ We,
                                            const int* __restrict__ flag,
                                            float* __restrict__ ee) {
  const int isbf = flag[1];
  __shared__ float es[NR * DEDIM];
  for (int i = threadIdx.x; i < NR * DEDIM; i += 256)
    es[i] = isbf ? ldf<1>(emb, i) : ldf<0>(emb, i);
  __syncthreads();
  for (int o = threadIdx.x; o < NR * HC; o += 256) {
    int r = o >> 7, j = o & 127;
    float acc = 0.f;
    if (isbf) { for (int d = 0; d < DEDIM; ++d) acc += es[r * DEDIM + d] * ldf<1>(We, d * HC + j); }
    else      { for (int d = 0; d < DEDIM; ++d) acc += es[r * DEDIM + d] * ldf<0>(We, d * HC + j); }
    ee[o] = acc;
  }
}

// q,k,v (bf16) and accum := x@Wskip (fp32). 8 nodes / block.
template <int ISBF>
__device__ __forceinline__ void qkvs_body(const void* __restrict__ x,
    const void* __restrict__ Wq, const void* __restrict__ Wk,
    const void* __restrict__ Wv, const void* __restrict__ Ws,
    bf16* __restrict__ qb, bf16* __restrict__ kb, bf16* __restrict__ vb,
    float* __restrict__ accum, float* xs, int n0) {
  for (int i = threadIdx.x; i < 8 * 128; i += 256) {
    int n = n0 + (i >> 7);
    xs[i] = (n < NN) ? ldf<ISBF>(x, (size_t)n * FF + (i & 127)) : 0.f;
  }
  __syncthreads();
  int j = threadIdx.x & 127;
  int g = threadIdx.x >> 7;          // node half: 0..1
  const float* xg = xs + g * 4 * 128;
  float aq[4] = {0, 0, 0, 0}, ak[4] = {0, 0, 0, 0};
  float av[4] = {0, 0, 0, 0}, asv[4] = {0, 0, 0, 0};
  for (int kk = 0; kk < 128; ++kk) {
    float wq = ldf<ISBF>(Wq, kk * HC + j);
    float wk = ldf<ISBF>(Wk, kk * HC + j);
    float wv = ldf<ISBF>(Wv, kk * HC + j);
    float ws = ldf<ISBF>(Ws, kk * HC + j);
#pragma unroll
    for (int n = 0; n < 4; ++n) {
      float xv = xg[n * 128 + kk];   // LDS broadcast within wave
      aq[n] += xv * wq; ak[n] += xv * wk; av[n] += xv * wv; asv[n] += xv * ws;
    }
  }
#pragma unroll
  for (int n = 0; n < 4; ++n) {
    int node = n0 + g * 4 + n;
    if (node < NN) {
      qb[(size_t)node * HC + j] = __float2bfloat16(aq[n]);
      kb[(size_t)node * HC + j] = __float2bfloat16(ak[n]);
      vb[(size_t)node * HC + j] = __float2bfloat16(av[n]);
      accum[(size_t)node * HC + j] = asv[n];   // skip connection seeds accum
    }
  }
}

__global__ __launch_bounds__(256) void k_qkvs(const void* __restrict__ x,
    const void* __restrict__ Wq, const void* __restrict__ Wk,
    const void* __restrict__ Wv, const void* __restrict__ Ws,
    const int* __restrict__ flag, bf16* __restrict__ qb,
    bf16* __restrict__ kb, bf16* __restrict__ vb, float* __restrict__ accum) {
  __shared__ float xs[8 * 128];
  int n0 = blockIdx.x * 8;
  if (flag[1]) qkvs_body<1>(x, Wq, Wk, Wv, Ws, qb, kb, vb, accum, xs, n0);
  else         qkvs_body<0>(x, Wq, Wk, Wv, Ws, qb, kb, vb, accum, xs, n0);
}

// shared logit computation: 4 head logits for one edge (q,k are our bf16 bufs)
__device__ __forceinline__ void edge_logits(const bf16* qrow, const bf16* krow,
                                            const float* erow, float* lg) {
  const uint4* q4 = (const uint4*)qrow;
  const uint4* k4 = (const uint4*)krow;
  const float4* e4 = (const float4*)erow;
  float acc[4] = {0, 0, 0, 0};
#pragma unroll
  for (int cc = 0; cc < 16; ++cc) {
    uint4 qv = q4[cc], kv = k4[cc];
    float4 ea = e4[2 * cc], eb = e4[2 * cc + 1];
    float s;
    s  = bflo(qv.x) * (bflo(kv.x) + ea.x);
    s += bfhi(qv.x) * (bfhi(kv.x) + ea.y);
    s += bflo(qv.y) * (bflo(kv.y) + ea.z);
    s += bfhi(qv.y) * (bfhi(kv.y) + ea.w);
    s += bflo(qv.z) * (bflo(kv.z) + eb.x);
    s += bfhi(qv.z) * (bfhi(kv.z) + eb.y);
    s += bflo(qv.w) * (bflo(kv.w) + eb.z);
    s += bfhi(qv.w) * (bfhi(kv.w) + eb.w);
    acc[cc >> 2] += s;
  }
  const float sc = 0.17677669529663687f;  // 1/sqrt(32)
#pragma unroll
  for (int h = 0; h < 4; ++h) lg[h] = acc[h] * sc;
}

// pass A: denom[dst][h] += exp(logit)  (no max-shift: |logit| << 88, cannot
// overflow fp32; softmax is shift-invariant so result matches reference)
__global__ __launch_bounds__(256) void k_att(const void* __restrict__ eidx,
    const void* __restrict__ etype, const bf16* __restrict__ qb,
    const bf16* __restrict__ kb, const float* __restrict__ ee,
    const int* __restrict__ flag, float* __restrict__ denom) {
  int e = blockIdx.x * 256 + threadIdx.x;
  if (e >= NE) return;
  const int is64 = flag[0];
  int src = idx_at(eidx, e, is64);
  int dst = idx_at(eidx, (long long)NE + e, is64);
  int et  = idx_at(etype, e, is64);
  src = min(max(src, 0), NN - 1);   // crash insurance (wrong-not-NaN on misdetect)
  dst = min(max(dst, 0), NN - 1);
  et  = min(max(et, 0), NR - 1);
  float lg[4];
  edge_logits(qb + (size_t)dst * HC, kb + (size_t)src * HC, ee + et * HC, lg);
  unsafeAtomicAdd(&denom[dst * NH + 0], __expf(lg[0]));
  unsafeAtomicAdd(&denom[dst * NH + 1], __expf(lg[1]));
  unsafeAtomicAdd(&denom[dst * NH + 2], __expf(lg[2]));
  unsafeAtomicAdd(&denom[dst * NH + 3], __expf(lg[3]));
}

// pass B: recompute logits, alpha = exp(lg)/denom[dst], accum += alpha*(v+e)
__global__ __launch_bounds__(256) void k_msg(const void* __restrict__ eidx,
    const void* __restrict__ etype, const bf16* __restrict__ qb,
    const bf16* __restrict__ kb, const bf16* __restrict__ vb,
    const float* __restrict__ ee, const int* __restrict__ flag,
    const float* __restrict__ denom, float* __restrict__ accum) {
  int e = blockIdx.x * 256 + threadIdx.x;
  if (e >= NE) return;
  const int is64 = flag[0];
  int src = idx_at(eidx, e, is64);
  int dst = idx_at(eidx, (long long)NE + e, is64);
  int et  = idx_at(etype, e, is64);
  src = min(max(src, 0), NN - 1);
  dst = min(max(dst, 0), NN - 1);
  et  = min(max(et, 0), NR - 1);
  float lg[4];
  const float* erow = ee + et * HC;
  edge_logits(qb + (size_t)dst * HC, kb + (size_t)src * HC, erow, lg);
  float4 dn = ((const float4*)denom)[dst];
  float alpha[4] = { __expf(lg[0]) / (dn.x + 1e-16f),
                     __expf(lg[1]) / (dn.y + 1e-16f),
                     __expf(lg[2]) / (dn.z + 1e-16f),
                     __expf(lg[3]) / (dn.w + 1e-16f) };
  const uint4* v4 = (const uint4*)(vb + (size_t)src * HC);
  const float4* e4 = (const float4*)erow;
  float* ab = accum + (size_t)dst * HC;
#pragma unroll
  for (int cc = 0; cc < 16; ++cc) {
    uint4 vv = v4[cc];
    float4 ea = e4[2 * cc], eb = e4[2 * cc + 1];
    float a = alpha[cc >> 2];
    int base = cc * 8;
    unsafeAtomicAdd(&ab[base + 0], (bflo(vv.x) + ea.x) * a);
    unsafeAtomicAdd(&ab[base + 1], (bfhi(vv.x) + ea.y) * a);
    unsafeAtomicAdd(&ab[base + 2], (bflo(vv.y) + ea.z) * a);
    unsafeAtomicAdd(&ab[base + 3], (bfhi(vv.y) + ea.w) * a);
    unsafeAtomicAdd(&ab[base + 4], (bflo(vv.z) + eb.x) * a);
    unsafeAtomicAdd(&ab[base + 5], (bfhi(vv.z) + eb.y) * a);
    unsafeAtomicAdd(&ab[base + 6], (bflo(vv.w) + eb.z) * a);
    unsafeAtomicAdd(&ab[base + 7], (bfhi(vv.w) + eb.w) * a);
  }
}

// final: out = accum (already includes skip), stored per detected out dtype.
// (overwrites the q scratch living in d_out)
__global__ __launch_bounds__(256) void k_final(const float* __restrict__ accum,
                                               void* __restrict__ out,
                                               const int* __restrict__ flag) {
  int i = blockIdx.x * 256 + threadIdx.x;  // 8 elements per thread
  if (i >= (NN * HC) / 8) return;
  float4 a = ((const float4*)accum)[2 * i];
  float4 b = ((const float4*)accum)[2 * i + 1];
  if (flag[1]) {
    uint4 o;
    o.x = pack2bf(a.x, a.y);
    o.y = pack2bf(a.z, a.w);
    o.z = pack2bf(b.x, b.y);
    o.w = pack2bf(b.z, b.w);
    ((uint4*)out)[i] = o;
  } else {
    ((float4*)out)[2 * i]     = a;
    ((float4*)out)[2 * i + 1] = b;
  }
}

// ---- launch -----------------------------------------------------------------
extern "C" void kernel_launch(void* const* d_in, const int* in_sizes, int n_in,
                              void* d_out, int out_size, void* d_ws, size_t ws_size,
                              hipStream_t stream) {
  const void* x     = d_in[0];
  const void* eidx  = d_in[1];   // [2,E]: first E = src, next E = dst
  const void* etype = d_in[2];
  const void* emb   = d_in[3];
  const void* Wq    = d_in[4];
  const void* Wk    = d_in[5];
  const void* Wv    = d_in[6];
  const void* We    = d_in[7];
  const void* Ws    = d_in[8];

  // workspace layout — total ~52.0 MB
  int*   flag  = (int*)d_ws;                       // 16 floats reserved
  float* ee    = (float*)d_ws + 16;                // 1024
  float* denom = ee + 1024;                        // N*H = 200000
  float* accum = denom + (size_t)NN * NH;          // N*HC = 6.4M fp32
  bf16*  kb    = (bf16*)(accum + (size_t)NN * HC); // 6.4M bf16
  bf16*  vb    = kb + (size_t)NN * HC;             // 6.4M bf16
  bf16*  qb    = (bf16*)d_out;                     // d_out doubles as q scratch

  k_detect<<<1, 128, 0, stream>>>((const int*)eidx, (const unsigned*)x, flag);
  k_init  <<<(NN * NH + 255) / 256, 256, 0, stream>>>(denom);
  k_ee    <<<1, 256, 0, stream>>>(emb, We, flag, ee);
  k_qkvs  <<<(NN + 7) / 8, 256, 0, stream>>>(x, Wq, Wk, Wv, Ws, flag, qb, kb, vb, accum);
  k_att   <<<(NE + 255) / 256, 256, 0, stream>>>(eidx, etype, qb, kb, ee, flag, denom);
  k_msg   <<<(NE + 255) / 256, 256, 0, stream>>>(eidx, etype, qb, kb, vb, ee, flag, denom, accum);
  k_final <<<((NN * HC / 8) + 255) / 256, 256, 0, stream>>>(accum, d_out, flag);
}

// Round 4
// 790.968 us; speedup vs baseline: 7.2708x; 7.2708x over previous
//
#include <hip/hip_runtime.h>
#include <hip/hip_bf16.h>

// Problem constants (from reference):
#define NN 50000   // nodes
#define FF 128     // in channels
#define NH 4       // heads
#define CH 32      // channels/head
#define HC 128     // NH*CH
#define NE 800000  // edges
#define NR 8       // relations
#define DEDIM 64   // edge emb dim

typedef __hip_bfloat16 bf16;

// ---- helpers ----------------------------------------------------------------
__device__ __forceinline__ float bflo(unsigned u) { return __uint_as_float(u << 16); }
__device__ __forceinline__ float bfhi(unsigned u) { return __uint_as_float(u & 0xFFFF0000u); }

__device__ __forceinline__ unsigned short f2bf(float f) {
  unsigned u = __float_as_uint(f);
  unsigned r = (u + 0x7FFFu + ((u >> 16) & 1u)) >> 16;  // round-nearest-even
  return (unsigned short)r;
}
__device__ __forceinline__ unsigned pack2bf(float lo, float hi) {
  return (unsigned)f2bf(lo) | ((unsigned)f2bf(hi) << 16);
}

// dtype-dispatched scalar load of a "float-like" input
template <int ISBF>
__device__ __forceinline__ float ldf(const void* p, size_t i) {
  if (ISBF) return __bfloat162float(((const bf16*)p)[i]);
  return ((const float*)p)[i];
}

// index load robust to int64/int32
__device__ __forceinline__ int idx_at(const void* p, long long i, int is64) {
  if (is64) { long long v = ((const long long*)p)[i]; return (int)v; }
  return ((const int*)p)[i];
}

// ---- detection ---------------------------------------------------------------
// flag[0]: 1 if edge_index is int64; flag[1]: 1 if float inputs are bf16
__global__ __launch_bounds__(128) void k_detect(const int* __restrict__ eidx32,
                                                const unsigned* __restrict__ xw,
                                                int* __restrict__ flag) {
  __shared__ int nzIdx, badBf;
  if (threadIdx.x == 0) { nzIdx = 0; badBf = 0; }
  __syncthreads();
  if (eidx32[2 * threadIdx.x + 1] != 0) atomicAdd(&nzIdx, 1);
  unsigned e = (xw[threadIdx.x] >> 7) & 0xFFu;  // exponent of low-half bf16
  if (e < 90u || e > 140u) atomicAdd(&badBf, 1);
  __syncthreads();
  if (threadIdx.x == 0) { flag[0] = (nzIdx == 0); flag[1] = (badBf == 0); }
}

// ---- small prep --------------------------------------------------------------
__global__ __launch_bounds__(256) void k_zero(int* __restrict__ hist) {
  int i = blockIdx.x * 256 + threadIdx.x;
  if (i < NN) hist[i] = 0;
}

// ee[r][j] = sum_d edge_emb[r][d] * We[d][j]   (8x128 fp32, one block)
__global__ __launch_bounds__(256) void k_ee(const void* __restrict__ emb,
                                            const void* __restrict__ We,
                                            const int* __restrict__ flag,
                                            float* __restrict__ ee) {
  const int isbf = flag[1];
  __shared__ float es[NR * DEDIM];
  for (int i = threadIdx.x; i < NR * DEDIM; i += 256)
    es[i] = isbf ? ldf<1>(emb, i) : ldf<0>(emb, i);
  __syncthreads();
  for (int o = threadIdx.x; o < NR * HC; o += 256) {
    int r = o >> 7, j = o & 127;
    float acc = 0.f;
    if (isbf) { for (int d = 0; d < DEDIM; ++d) acc += es[r * DEDIM + d] * ldf<1>(We, d * HC + j); }
    else      { for (int d = 0; d < DEDIM; ++d) acc += es[r * DEDIM + d] * ldf<0>(We, d * HC + j); }
    ee[o] = acc;
  }
}

// ---- q,k,v,skip projections --------------------------------------------------
template <int ISBF>
__device__ __forceinline__ void qkvs_body(const void* __restrict__ x,
    const void* __restrict__ Wq, const void* __restrict__ Wk,
    const void* __restrict__ Wv, const void* __restrict__ Ws,
    bf16* __restrict__ qb, bf16* __restrict__ kb, bf16* __restrict__ vb,
    bf16* __restrict__ skipb, float* xs, int n0) {
  for (int i = threadIdx.x; i < 8 * 128; i += 256) {
    int n = n0 + (i >> 7);
    xs[i] = (n < NN) ? ldf<ISBF>(x, (size_t)n * FF + (i & 127)) : 0.f;
  }
  __syncthreads();
  int j = threadIdx.x & 127;
  int g = threadIdx.x >> 7;          // node half: 0..1
  const float* xg = xs + g * 4 * 128;
  float aq[4] = {0, 0, 0, 0}, ak[4] = {0, 0, 0, 0};
  float av[4] = {0, 0, 0, 0}, asv[4] = {0, 0, 0, 0};
  for (int kk = 0; kk < 128; ++kk) {
    float wq = ldf<ISBF>(Wq, kk * HC + j);
    float wk = ldf<ISBF>(Wk, kk * HC + j);
    float wv = ldf<ISBF>(Wv, kk * HC + j);
    float ws = ldf<ISBF>(Ws, kk * HC + j);
#pragma unroll
    for (int n = 0; n < 4; ++n) {
      float xv = xg[n * 128 + kk];   // LDS broadcast within wave
      aq[n] += xv * wq; ak[n] += xv * wk; av[n] += xv * wv; asv[n] += xv * ws;
    }
  }
#pragma unroll
  for (int n = 0; n < 4; ++n) {
    int node = n0 + g * 4 + n;
    if (node < NN) {
      qb[(size_t)node * HC + j]    = __float2bfloat16(aq[n]);
      kb[(size_t)node * HC + j]    = __float2bfloat16(ak[n]);
      vb[(size_t)node * HC + j]    = __float2bfloat16(av[n]);
      skipb[(size_t)node * HC + j] = __float2bfloat16(asv[n]);
    }
  }
}

__global__ __launch_bounds__(256) void k_qkvs(const void* __restrict__ x,
    const void* __restrict__ Wq, const void* __restrict__ Wk,
    const void* __restrict__ Wv, const void* __restrict__ Ws,
    const int* __restrict__ flag, bf16* __restrict__ qb,
    bf16* __restrict__ kb, bf16* __restrict__ vb, bf16* __restrict__ skipb) {
  __shared__ float xs[8 * 128];
  int n0 = blockIdx.x * 8;
  if (flag[1]) qkvs_body<1>(x, Wq, Wk, Wv, Ws, qb, kb, vb, skipb, xs, n0);
  else         qkvs_body<0>(x, Wq, Wk, Wv, Ws, qb, kb, vb, skipb, xs, n0);
}

// ---- counting sort by dst ----------------------------------------------------
__global__ __launch_bounds__(256) void k_hist(const void* __restrict__ eidx,
                                              const int* __restrict__ flag,
                                              int* __restrict__ hist) {
  int e = blockIdx.x * 256 + threadIdx.x;
  if (e >= NE) return;
  int dst = idx_at(eidx, (long long)NE + e, flag[0]);
  dst = min(max(dst, 0), NN - 1);
  atomicAdd(&hist[dst], 1);
}

// single-block exclusive scan over 50000 bins -> rowptr[NN+1]; cursor = rowptr
__global__ __launch_bounds__(1024) void k_scan(const int* __restrict__ hist,
                                               int* __restrict__ rowptr,
                                               int* __restrict__ cursor) {
  __shared__ int s[1024];
  __shared__ int carry_s;
  int tid = threadIdx.x;
  if (tid == 0) carry_s = 0;
  __syncthreads();
  for (int base = 0; base < NN; base += 1024) {
    int i = base + tid;
    int v = (i < NN) ? hist[i] : 0;
    s[tid] = v;
    __syncthreads();
    for (int off = 1; off < 1024; off <<= 1) {
      int t = (tid >= off) ? s[tid - off] : 0;
      __syncthreads();
      s[tid] += t;
      __syncthreads();
    }
    int incl = s[tid];
    int carry = carry_s;
    int excl = carry + incl - v;
    if (i < NN) { rowptr[i] = excl; cursor[i] = excl; }
    __syncthreads();
    if (tid == 1023) carry_s = carry + s[1023];
    __syncthreads();
  }
  if (tid == 0) rowptr[NN] = carry_s;
}

// scatter edge ids into dst-sorted order
__global__ __launch_bounds__(256) void k_scatter(const void* __restrict__ eidx,
                                                 const int* __restrict__ flag,
                                                 int* __restrict__ cursor,
                                                 int* __restrict__ rec) {
  int e = blockIdx.x * 256 + threadIdx.x;
  if (e >= NE) return;
  int dst = idx_at(eidx, (long long)NE + e, flag[0]);
  dst = min(max(dst, 0), NN - 1);
  int pos = atomicAdd(&cursor[dst], 1);
  rec[pos] = e;
}

// ---- logits ------------------------------------------------------------------
__device__ __forceinline__ void edge_logits(const bf16* qrow, const bf16* krow,
                                            const float* erow, float* lg) {
  const uint4* q4 = (const uint4*)qrow;
  const uint4* k4 = (const uint4*)krow;
  const float4* e4 = (const float4*)erow;
  float acc[4] = {0, 0, 0, 0};
#pragma unroll
  for (int cc = 0; cc < 16; ++cc) {
    uint4 qv = q4[cc], kv = k4[cc];
    float4 ea = e4[2 * cc], eb = e4[2 * cc + 1];
    float s;
    s  = bflo(qv.x) * (bflo(kv.x) + ea.x);
    s += bfhi(qv.x) * (bfhi(kv.x) + ea.y);
    s += bflo(qv.y) * (bflo(kv.y) + ea.z);
    s += bfhi(qv.y) * (bfhi(kv.y) + ea.w);
    s += bflo(qv.z) * (bflo(kv.z) + eb.x);
    s += bfhi(qv.z) * (bfhi(kv.z) + eb.y);
    s += bflo(qv.w) * (bflo(kv.w) + eb.z);
    s += bfhi(qv.w) * (bfhi(kv.w) + eb.w);
    acc[cc >> 2] += s;
  }
  const float sc = 0.17677669529663687f;  // 1/sqrt(32)
#pragma unroll
  for (int h = 0; h < 4; ++h) lg[h] = acc[h] * sc;
}

// over sorted positions: exq[p] = 4 x bf16( exp(logit) ). No atomics.
// (no max-shift: |logit| << 88, softmax is shift-invariant)
__global__ __launch_bounds__(256) void k_att(const int* __restrict__ rec,
    const void* __restrict__ eidx, const void* __restrict__ etype,
    const bf16* __restrict__ qb, const bf16* __restrict__ kb,
    const float* __restrict__ ee, const int* __restrict__ flag,
    uint2* __restrict__ exq) {
  int p = blockIdx.x * 256 + threadIdx.x;
  if (p >= NE) return;
  const int is64 = flag[0];
  int e = rec[p];
  int src = idx_at(eidx, e, is64);
  int dst = idx_at(eidx, (long long)NE + e, is64);
  int et  = idx_at(etype, e, is64);
  src = min(max(src, 0), NN - 1);
  dst = min(max(dst, 0), NN - 1);
  et  = min(max(et, 0), NR - 1);
  float lg[4];
  edge_logits(qb + (size_t)dst * HC, kb + (size_t)src * HC, ee + et * HC, lg);
  uint2 o;
  o.x = pack2bf(__expf(lg[0]), __expf(lg[1]));
  o.y = pack2bf(__expf(lg[2]), __expf(lg[3]));
  exq[p] = o;
}

// ---- dst-owned gather: softmax denom + weighted message + skip + store -------
__global__ __launch_bounds__(256) void k_gather(const int* __restrict__ rowptr,
    const int* __restrict__ rec, const uint2* __restrict__ exq,
    const void* __restrict__ eidx, const void* __restrict__ etype,
    const bf16* __restrict__ vb, const float* __restrict__ ee,
    const bf16* __restrict__ skipb, const int* __restrict__ flag,
    void* __restrict__ out) {
  int n = blockIdx.x * 2 + (threadIdx.x >> 7);   // 2 nodes / block
  int j = threadIdx.x & 127;
  int h = j >> 5;
  const int is64 = flag[0];
  int beg = rowptr[n], end = rowptr[n + 1];
  // pass 1: softmax denominator for this head (broadcast loads)
  float dn = 0.f;
  for (int p = beg; p < end; ++p) {
    uint2 q = exq[p];
    unsigned w = (h & 2) ? q.y : q.x;
    dn += (h & 1) ? bfhi(w) : bflo(w);
  }
  float inv = 1.f / (dn + 1e-16f);
  // pass 2: weighted message
  float acc = 0.f;
  for (int p = beg; p < end; ++p) {
    int e = rec[p];
    int src = idx_at(eidx, e, is64);
    int et  = idx_at(etype, e, is64);
    src = min(max(src, 0), NN - 1);
    et  = min(max(et, 0), NR - 1);
    uint2 q = exq[p];
    unsigned w = (h & 2) ? q.y : q.x;
    float exh = (h & 1) ? bfhi(w) : bflo(w);
    float vj = __bfloat162float(vb[(size_t)src * HC + j]);
    float ej = ee[et * HC + j];
    acc += (vj + ej) * exh;
  }
  float o = acc * inv + __bfloat162float(skipb[(size_t)n * HC + j]);
  if (flag[1]) ((unsigned short*)out)[(size_t)n * HC + j] = f2bf(o);
  else         ((float*)out)[(size_t)n * HC + j] = o;
}

// ---- launch -----------------------------------------------------------------
extern "C" void kernel_launch(void* const* d_in, const int* in_sizes, int n_in,
                              void* d_out, int out_size, void* d_ws, size_t ws_size,
                              hipStream_t stream) {
  const void* x     = d_in[0];
  const void* eidx  = d_in[1];   // [2,E]: first E = src, next E = dst
  const void* etype = d_in[2];
  const void* emb   = d_in[3];
  const void* Wq    = d_in[4];
  const void* Wk    = d_in[5];
  const void* Wv    = d_in[6];
  const void* We    = d_in[7];
  const void* Ws    = d_in[8];

  // workspace layout (float units) — total ~48.4 MB (proven-safe < 52 MB)
  float* base   = (float*)d_ws;
  int*   flag   = (int*)base;                       // 16
  float* ee     = base + 16;                        // 1024
  int*   rowptr = (int*)(base + 1040);              // NN+1 (50001) -> pad 50004
  int*   cursor = (int*)(base + 51044);             // NN, doubles as hist
  int*   rec    = (int*)(base + 101044);            // NE
  uint2* exq    = (uint2*)(base + 901044);          // NE uint2 (4xbf16/edge)
  bf16*  skipb  = (bf16*)(base + 2501044);          // NN*HC bf16
  bf16*  kb     = (bf16*)(base + 5701044);          // NN*HC bf16
  bf16*  vb     = (bf16*)(base + 8901044);          // NN*HC bf16
  bf16*  qb     = (bf16*)d_out;                     // d_out doubles as q scratch

  k_detect <<<1, 128, 0, stream>>>((const int*)eidx, (const unsigned*)x, flag);
  k_zero   <<<(NN + 255) / 256, 256, 0, stream>>>(cursor);
  k_ee     <<<1, 256, 0, stream>>>(emb, We, flag, ee);
  k_qkvs   <<<(NN + 7) / 8, 256, 0, stream>>>(x, Wq, Wk, Wv, Ws, flag, qb, kb, vb, skipb);
  k_hist   <<<(NE + 255) / 256, 256, 0, stream>>>(eidx, flag, cursor);
  k_scan   <<<1, 1024, 0, stream>>>(cursor, rowptr, cursor);
  // NOTE: k_scan reads hist (=cursor) and rewrites cursor in-place with start
  // offsets; safe because each i is read before written by the same block pass.
  k_scatter<<<(NE + 255) / 256, 256, 0, stream>>>(eidx, flag, cursor, rec);
  k_att    <<<(NE + 255) / 256, 256, 0, stream>>>(rec, eidx, etype, qb, kb, ee, flag, exq);
  k_gather <<<NN / 2, 256, 0, stream>>>(rowptr, rec, exq, eidx, etype, vb, ee, skipb, flag, d_out);
}

// Round 5
// 455.587 us; speedup vs baseline: 12.6232x; 1.7362x over previous
//
#include <hip/hip_runtime.h>
#include <hip/hip_bf16.h>

// Problem constants (from reference):
#define NN 50000   // nodes
#define FF 128     // in channels
#define NH 4       // heads
#define CH 32      // channels/head
#define HC 128     // NH*CH
#define NE 800000  // edges
#define NR 8       // relations
#define DEDIM 64   // edge emb dim
#define NBLK 196   // ceil(NN/256)

typedef __hip_bfloat16 bf16;

// ---- helpers ----------------------------------------------------------------
__device__ __forceinline__ float bflo(unsigned u) { return __uint_as_float(u << 16); }
__device__ __forceinline__ float bfhi(unsigned u) { return __uint_as_float(u & 0xFFFF0000u); }

__device__ __forceinline__ unsigned short f2bf(float f) {
  unsigned u = __float_as_uint(f);
  unsigned r = (u + 0x7FFFu + ((u >> 16) & 1u)) >> 16;  // round-nearest-even
  return (unsigned short)r;
}
__device__ __forceinline__ unsigned pack2bf(float lo, float hi) {
  return (unsigned)f2bf(lo) | ((unsigned)f2bf(hi) << 16);
}

// dtype-dispatched scalar load of a "float-like" input
template <int ISBF>
__device__ __forceinline__ float ldf(const void* p, size_t i) {
  if (ISBF) return __bfloat162float(((const bf16*)p)[i]);
  return ((const float*)p)[i];
}

// index load robust to int64/int32
__device__ __forceinline__ int idx_at(const void* p, long long i, int is64) {
  if (is64) { long long v = ((const long long*)p)[i]; return (int)v; }
  return ((const int*)p)[i];
}

// ---- prep: zero hist (blocks 0..NBLK-1) + detect + ee (block NBLK) ----------
// flag[0]: 1 if edge_index is int64; flag[1]: 1 if float inputs are bf16
__global__ __launch_bounds__(256) void k_prep(const int* __restrict__ eidx32,
    const unsigned* __restrict__ xw, const void* __restrict__ emb,
    const void* __restrict__ We, int* __restrict__ flag,
    int* __restrict__ hist, float* __restrict__ ee) {
  if (blockIdx.x < NBLK) {
    int i = blockIdx.x * 256 + threadIdx.x;
    if (i < NN) hist[i] = 0;
    return;
  }
  __shared__ int nzIdx, badBf;
  __shared__ float es[NR * DEDIM];
  if (threadIdx.x == 0) { nzIdx = 0; badBf = 0; }
  __syncthreads();
  if (threadIdx.x < 128) {
    if (eidx32[2 * threadIdx.x + 1] != 0) atomicAdd(&nzIdx, 1);
    unsigned e = (xw[threadIdx.x] >> 7) & 0xFFu;  // exponent of low-half bf16
    if (e < 90u || e > 140u) atomicAdd(&badBf, 1);
  }
  __syncthreads();
  const int isbf = (badBf == 0);
  if (threadIdx.x == 0) { flag[0] = (nzIdx == 0); flag[1] = isbf; }
  for (int i = threadIdx.x; i < NR * DEDIM; i += 256)
    es[i] = isbf ? ldf<1>(emb, i) : ldf<0>(emb, i);
  __syncthreads();
  for (int o = threadIdx.x; o < NR * HC; o += 256) {
    int r = o >> 7, j = o & 127;
    float acc = 0.f;
    if (isbf) { for (int d = 0; d < DEDIM; ++d) acc += es[r * DEDIM + d] * ldf<1>(We, d * HC + j); }
    else      { for (int d = 0; d < DEDIM; ++d) acc += es[r * DEDIM + d] * ldf<0>(We, d * HC + j); }
    ee[o] = acc;
  }
}

// ---- q (bf16), packed k|v (bf16x2), skip -> d_out. 8 nodes / block. ---------
template <int ISBF>
__device__ __forceinline__ void qkvs_body(const void* __restrict__ x,
    const void* __restrict__ Wq, const void* __restrict__ Wk,
    const void* __restrict__ Wv, const void* __restrict__ Ws,
    unsigned short* __restrict__ qb, unsigned* __restrict__ kvb,
    void* __restrict__ out, float* xs, int n0) {
  for (int i = threadIdx.x; i < 8 * 128; i += 256) {
    int n = n0 + (i >> 7);
    xs[i] = ldf<ISBF>(x, (size_t)n * FF + (i & 127));   // NN%8==0: always valid
  }
  __syncthreads();
  int j = threadIdx.x & 127;
  int g = threadIdx.x >> 7;          // node half: 0..1
  const float* xg = xs + g * 4 * 128;
  float aq[4] = {0, 0, 0, 0}, ak[4] = {0, 0, 0, 0};
  float av[4] = {0, 0, 0, 0}, asv[4] = {0, 0, 0, 0};
  for (int kk = 0; kk < 128; kk += 4) {
    float wq[4], wk[4], wv[4], wsk[4];
#pragma unroll
    for (int t = 0; t < 4; ++t) {
      wq[t]  = ldf<ISBF>(Wq, (size_t)(kk + t) * HC + j);
      wk[t]  = ldf<ISBF>(Wk, (size_t)(kk + t) * HC + j);
      wv[t]  = ldf<ISBF>(Wv, (size_t)(kk + t) * HC + j);
      wsk[t] = ldf<ISBF>(Ws, (size_t)(kk + t) * HC + j);
    }
#pragma unroll
    for (int n = 0; n < 4; ++n) {
      const float4 xv = *(const float4*)(xg + n * 128 + kk);
      aq[n]  += xv.x * wq[0]  + xv.y * wq[1]  + xv.z * wq[2]  + xv.w * wq[3];
      ak[n]  += xv.x * wk[0]  + xv.y * wk[1]  + xv.z * wk[2]  + xv.w * wk[3];
      av[n]  += xv.x * wv[0]  + xv.y * wv[1]  + xv.z * wv[2]  + xv.w * wv[3];
      asv[n] += xv.x * wsk[0] + xv.y * wsk[1] + xv.z * wsk[2] + xv.w * wsk[3];
    }
  }
#pragma unroll
  for (int n = 0; n < 4; ++n) {
    size_t idx = (size_t)(n0 + g * 4 + n) * HC + j;
    qb[idx]  = f2bf(aq[n]);
    kvb[idx] = pack2bf(ak[n], av[n]);   // k in low16, v in high16
    if (ISBF) ((unsigned short*)out)[idx] = f2bf(asv[n]);
    else      ((float*)out)[idx] = asv[n];
  }
}

__global__ __launch_bounds__(256) void k_qkvs(const void* __restrict__ x,
    const void* __restrict__ Wq, const void* __restrict__ Wk,
    const void* __restrict__ Wv, const void* __restrict__ Ws,
    const int* __restrict__ flag, unsigned short* __restrict__ qb,
    unsigned* __restrict__ kvb, void* __restrict__ out) {
  __shared__ float xs[8 * 128];
  int n0 = blockIdx.x * 8;
  if (flag[1]) qkvs_body<1>(x, Wq, Wk, Wv, Ws, qb, kvb, out, xs, n0);
  else         qkvs_body<0>(x, Wq, Wk, Wv, Ws, qb, kvb, out, xs, n0);
}

// ---- counting sort by dst ----------------------------------------------------
__global__ __launch_bounds__(256) void k_hist(const void* __restrict__ eidx,
                                              const int* __restrict__ flag,
                                              int* __restrict__ hist) {
  int e = blockIdx.x * 256 + threadIdx.x;
  if (e >= NE) return;
  int dst = idx_at(eidx, (long long)NE + e, flag[0]);
  dst = min(max(dst, 0), NN - 1);
  atomicAdd(&hist[dst], 1);
}

// two-level scan: block sums -> scan sums -> local scan + offset
__global__ __launch_bounds__(256) void k_scan1(const int* __restrict__ hist,
                                               int* __restrict__ bsum) {
  __shared__ int red[4];
  int i = blockIdx.x * 256 + threadIdx.x;
  int v = (i < NN) ? hist[i] : 0;
#pragma unroll
  for (int m = 1; m < 64; m <<= 1) v += __shfl_xor(v, m);
  if ((threadIdx.x & 63) == 0) red[threadIdx.x >> 6] = v;
  __syncthreads();
  if (threadIdx.x == 0) bsum[blockIdx.x] = red[0] + red[1] + red[2] + red[3];
}

__global__ __launch_bounds__(256) void k_scan2(const int* __restrict__ bsum,
                                               int* __restrict__ bexc) {
  __shared__ int s[256];
  int t = threadIdx.x;
  int v = (t < NBLK) ? bsum[t] : 0;
  s[t] = v;
  __syncthreads();
  for (int off = 1; off < 256; off <<= 1) {
    int u = (t >= off) ? s[t - off] : 0;
    __syncthreads();
    s[t] += u;
    __syncthreads();
  }
  if (t < NBLK) bexc[t] = s[t] - v;
}

__global__ __launch_bounds__(256) void k_scan3(const int* __restrict__ hist,
    const int* __restrict__ bexc, int* __restrict__ rowptr,
    int* __restrict__ cursor) {
  __shared__ int s[256];
  int t = threadIdx.x;
  int i = blockIdx.x * 256 + t;
  int v = (i < NN) ? hist[i] : 0;
  s[t] = v;
  __syncthreads();
  for (int off = 1; off < 256; off <<= 1) {
    int u = (t >= off) ? s[t - off] : 0;
    __syncthreads();
    s[t] += u;
    __syncthreads();
  }
  int excl = bexc[blockIdx.x] + s[t] - v;
  if (i < NN) { rowptr[i] = excl; cursor[i] = excl; }  // cursor aliases hist: block-local RAW, safe
  if (i == 0) rowptr[NN] = NE;   // all edges binned (dst clamped)
}

// scatter packed (src<<3 | et) into dst-sorted order
__global__ __launch_bounds__(256) void k_scatter(const void* __restrict__ eidx,
    const void* __restrict__ etype, const int* __restrict__ flag,
    int* __restrict__ cursor, int* __restrict__ srcet) {
  int e = blockIdx.x * 256 + threadIdx.x;
  if (e >= NE) return;
  const int is64 = flag[0];
  int src = idx_at(eidx, e, is64);
  int dst = idx_at(eidx, (long long)NE + e, is64);
  int et  = idx_at(etype, e, is64);
  src = min(max(src, 0), NN - 1);
  dst = min(max(dst, 0), NN - 1);
  et  = min(max(et, 0), NR - 1);
  int pos = atomicAdd(&cursor[dst], 1);
  srcet[pos] = (src << 3) | et;
}

// ---- fused attention+gather: logits via lane-split + shuffle reduce,
// single loop accumulates denom and message; out = msg/denom + skip ----------
__global__ __launch_bounds__(256) void k_gather(const int* __restrict__ rowptr,
    const int* __restrict__ srcet, const unsigned short* __restrict__ qb,
    const unsigned* __restrict__ kvb, const float* __restrict__ ee,
    const int* __restrict__ flag, void* __restrict__ out) {
  int n = blockIdx.x * 2 + (threadIdx.x >> 7);   // wave-uniform
  int j = threadIdx.x & 127;                      // channel; head = j>>5
  int beg = __builtin_amdgcn_readfirstlane(rowptr[n]);
  int end = __builtin_amdgcn_readfirstlane(rowptr[n + 1]);
  float qj = __uint_as_float(((unsigned)qb[(size_t)n * HC + j]) << 16);
  const float sc = 0.17677669529663687f;  // 1/sqrt(32)
  float dn = 0.f, acc = 0.f;
  int p = beg;
  for (; p + 2 <= end; p += 2) {
    int se0 = srcet[p], se1 = srcet[p + 1];
    unsigned u0 = kvb[(size_t)(se0 >> 3) * HC + j];
    unsigned u1 = kvb[(size_t)(se1 >> 3) * HC + j];
    float e0 = ee[((se0 & 7) << 7) + j];
    float e1 = ee[((se1 & 7) << 7) + j];
    float p0 = qj * (bflo(u0) + e0);
    float p1 = qj * (bflo(u1) + e1);
    p0 += __shfl_xor(p0, 1);  p1 += __shfl_xor(p1, 1);
    p0 += __shfl_xor(p0, 2);  p1 += __shfl_xor(p1, 2);
    p0 += __shfl_xor(p0, 4);  p1 += __shfl_xor(p1, 4);
    p0 += __shfl_xor(p0, 8);  p1 += __shfl_xor(p1, 8);
    p0 += __shfl_xor(p0, 16); p1 += __shfl_xor(p1, 16);
    float x0 = __expf(p0 * sc), x1 = __expf(p1 * sc);
    dn += x0 + x1;
    acc += (bfhi(u0) + e0) * x0 + (bfhi(u1) + e1) * x1;
  }
  if (p < end) {
    int se0 = srcet[p];
    unsigned u0 = kvb[(size_t)(se0 >> 3) * HC + j];
    float e0 = ee[((se0 & 7) << 7) + j];
    float p0 = qj * (bflo(u0) + e0);
    p0 += __shfl_xor(p0, 1);
    p0 += __shfl_xor(p0, 2);
    p0 += __shfl_xor(p0, 4);
    p0 += __shfl_xor(p0, 8);
    p0 += __shfl_xor(p0, 16);
    float x0 = __expf(p0 * sc);
    dn += x0;
    acc += (bfhi(u0) + e0) * x0;
  }
  float o = acc / (dn + 1e-16f);
  size_t oi = (size_t)n * HC + j;
  if (flag[1]) {  // skip was stored dtype-matched in d_out; same-thread RAW, safe
    o += __uint_as_float(((unsigned)((const unsigned short*)out)[oi]) << 16);
    ((unsigned short*)out)[oi] = f2bf(o);
  } else {
    o += ((const float*)out)[oi];
    ((float*)out)[oi] = o;
  }
}

// ---- launch -----------------------------------------------------------------
extern "C" void kernel_launch(void* const* d_in, const int* in_sizes, int n_in,
                              void* d_out, int out_size, void* d_ws, size_t ws_size,
                              hipStream_t stream) {
  const void* x     = d_in[0];
  const void* eidx  = d_in[1];   // [2,E]: first E = src, next E = dst
  const void* etype = d_in[2];
  const void* emb   = d_in[3];
  const void* Wq    = d_in[4];
  const void* Wk    = d_in[5];
  const void* Wv    = d_in[6];
  const void* We    = d_in[7];
  const void* Ws    = d_in[8];

  // workspace layout (float units) — total ~42.0 MB (< proven-safe 48.4 MB)
  float* base   = (float*)d_ws;
  int*   flag   = (int*)base;                       // 16
  float* ee     = base + 16;                        // 1024 -> 1040
  int*   rowptr = (int*)(base + 1040);              // 50001 -> pad 50004
  int*   cursor = (int*)(base + 51044);             // 50000 (doubles as hist)
  int*   bsum   = (int*)(base + 101044);            // 196 -> pad 256
  int*   bexc   = (int*)(base + 101300);            // 196 -> pad 268 (align 16)
  int*   srcet  = (int*)(base + 101568);            // NE -> 901568
  unsigned short* qb  = (unsigned short*)(base + 901568);   // NN*HC bf16 (3.2M fl)
  unsigned*       kvb = (unsigned*)(base + 4101568);        // NN*HC uint (6.4M fl)
  // end: 10501568 floats = 42.0 MB

  k_prep   <<<NBLK + 1, 256, 0, stream>>>((const int*)eidx, (const unsigned*)x,
                                          emb, We, flag, cursor, ee);
  k_qkvs   <<<NN / 8, 256, 0, stream>>>(x, Wq, Wk, Wv, Ws, flag, qb, kvb, d_out);
  k_hist   <<<NE / 256, 256, 0, stream>>>(eidx, flag, cursor);
  k_scan1  <<<NBLK, 256, 0, stream>>>(cursor, bsum);
  k_scan2  <<<1, 256, 0, stream>>>(bsum, bexc);
  k_scan3  <<<NBLK, 256, 0, stream>>>(cursor, bexc, rowptr, cursor);
  k_scatter<<<NE / 256, 256, 0, stream>>>(eidx, etype, flag, cursor, srcet);
  k_gather <<<NN / 2, 256, 0, stream>>>(rowptr, srcet, qb, kvb, ee, flag, d_out);
}

// Round 6
// 360.056 us; speedup vs baseline: 15.9724x; 1.2653x over previous
//
#include <hip/hip_runtime.h>
#include <hip/hip_bf16.h>

// Problem constants (from reference):
#define NN 50000   // nodes
#define FF 128     // in channels
#define NH 4       // heads
#define CH 32      // channels/head
#define HC 128     // NH*CH
#define NE 800000  // edges
#define NR 8       // relations
#define DEDIM 64   // edge emb dim
#define NBLK 196   // ceil(NN/256)
#define QBLK 200   // M-chunk blocks per matrix in qkvs
#define MTILES 3125 // NN/16

typedef __hip_bfloat16 bf16;
typedef __attribute__((ext_vector_type(8))) short short8;   // 8 x bf16 (4 VGPR)
typedef __attribute__((ext_vector_type(4))) float f32x4;

// ---- helpers ----------------------------------------------------------------
__device__ __forceinline__ float bflo(unsigned u) { return __uint_as_float(u << 16); }
__device__ __forceinline__ float bfhi(unsigned u) { return __uint_as_float(u & 0xFFFF0000u); }

__device__ __forceinline__ unsigned short f2bf(float f) {
  unsigned u = __float_as_uint(f);
  unsigned r = (u + 0x7FFFu + ((u >> 16) & 1u)) >> 16;  // round-nearest-even
  return (unsigned short)r;
}
__device__ __forceinline__ unsigned pack2bf(float lo, float hi) {
  return (unsigned)f2bf(lo) | ((unsigned)f2bf(hi) << 16);
}

template <int ISBF>
__device__ __forceinline__ float ldf(const void* p, size_t i) {
  if (ISBF) return __bfloat162float(((const bf16*)p)[i]);
  return ((const float*)p)[i];
}

__device__ __forceinline__ int idx_at(const void* p, long long i, int is64) {
  if (is64) { long long v = ((const long long*)p)[i]; return (int)v; }
  return ((const int*)p)[i];
}

// ---- prep: zero hist (blocks 0..NBLK-1) + detect + ee (block NBLK) ----------
// flag[0]: 1 if edge_index is int64; flag[1]: 1 if float inputs are bf16
__global__ __launch_bounds__(256) void k_prep(const int* __restrict__ eidx32,
    const unsigned* __restrict__ xw, const void* __restrict__ emb,
    const void* __restrict__ We, int* __restrict__ flag,
    int* __restrict__ hist, float* __restrict__ ee) {
  if (blockIdx.x < NBLK) {
    int i = blockIdx.x * 256 + threadIdx.x;
    if (i < NN) hist[i] = 0;
    return;
  }
  __shared__ int nzIdx, badBf;
  __shared__ float es[NR * DEDIM];
  if (threadIdx.x == 0) { nzIdx = 0; badBf = 0; }
  __syncthreads();
  if (threadIdx.x < 128) {
    if (eidx32[2 * threadIdx.x + 1] != 0) atomicAdd(&nzIdx, 1);
    unsigned e = (xw[threadIdx.x] >> 7) & 0xFFu;  // exponent of low-half bf16
    if (e < 90u || e > 140u) atomicAdd(&badBf, 1);
  }
  __syncthreads();
  const int isbf = (badBf == 0);
  if (threadIdx.x == 0) { flag[0] = (nzIdx == 0); flag[1] = isbf; }
  for (int i = threadIdx.x; i < NR * DEDIM; i += 256)
    es[i] = isbf ? ldf<1>(emb, i) : ldf<0>(emb, i);
  __syncthreads();
  for (int o = threadIdx.x; o < NR * HC; o += 256) {
    int r = o >> 7, j = o & 127;
    float acc = 0.f;
    if (isbf) { for (int d = 0; d < DEDIM; ++d) acc += es[r * DEDIM + d] * ldf<1>(We, d * HC + j); }
    else      { for (int d = 0; d < DEDIM; ++d) acc += es[r * DEDIM + d] * ldf<0>(We, d * HC + j); }
    ee[o] = acc;
  }
}

// ---- MFMA projection: grid = 4 matrices x QBLK chunks. Each block stages its
// W transposed in LDS (bf16), hoists B-frags to registers, grid-strides M.
// mat 0 -> qb (bf16), 1 -> kvb low16 (k), 2 -> kvb high16 (v), 3 -> skip in out.
#define WT_STRIDE 136   // bf16 elems; 272 B rows: 16B-aligned, 2-way max bank alias

template <int ISBF>
__device__ __forceinline__ void qkvs_mfma_body(const void* __restrict__ x,
    const void* __restrict__ W, int mat, int mc,
    unsigned short* __restrict__ qb, unsigned short* __restrict__ kv16,
    void* __restrict__ out, unsigned short* wt) {
  // stage W^T into LDS as bf16
  for (int i = threadIdx.x; i < FF * HC; i += 256) {
    int k = i >> 7, n = i & 127;
    unsigned short v = ISBF ? ((const unsigned short*)W)[i]
                            : f2bf(((const float*)W)[i]);
    wt[n * WT_STRIDE + k] = v;
  }
  __syncthreads();
  const int lane = threadIdx.x & 63;
  const int wv   = threadIdx.x >> 6;   // wave 0..3: owns cols [32w, 32w+32)
  const int quad = lane >> 4;
  const int lr   = lane & 15;
  // hoist B-frags: 2 n-tiles x 4 k-blocks
  short8 bfrag[2][4];
#pragma unroll
  for (int t = 0; t < 2; ++t) {
    int ncol = wv * 32 + t * 16 + lr;
#pragma unroll
    for (int kb = 0; kb < 4; ++kb)
      bfrag[t][kb] = *(const short8*)&wt[ncol * WT_STRIDE + kb * 32 + quad * 8];
  }
  const unsigned short* xu = (const unsigned short*)x;
  const float* xf = (const float*)x;
  for (int mt = mc; mt < MTILES; mt += QBLK) {
    int m0 = mt * 16;
    // A-frags: row m0+lr, k = kb*32 + quad*8 .. +8
    short8 afrag[4];
#pragma unroll
    for (int kb = 0; kb < 4; ++kb) {
      size_t off = (size_t)(m0 + lr) * FF + kb * 32 + quad * 8;
      if (ISBF) {
        afrag[kb] = *(const short8*)(xu + off);
      } else {
        float4 fa = *(const float4*)(xf + off);
        float4 fb = *(const float4*)(xf + off + 4);
        short8 a;
        a[0] = (short)f2bf(fa.x); a[1] = (short)f2bf(fa.y);
        a[2] = (short)f2bf(fa.z); a[3] = (short)f2bf(fa.w);
        a[4] = (short)f2bf(fb.x); a[5] = (short)f2bf(fb.y);
        a[6] = (short)f2bf(fb.z); a[7] = (short)f2bf(fb.w);
        afrag[kb] = a;
      }
    }
    f32x4 acc0 = {0.f, 0.f, 0.f, 0.f}, acc1 = {0.f, 0.f, 0.f, 0.f};
#pragma unroll
    for (int kb = 0; kb < 4; ++kb) {
      acc0 = __builtin_amdgcn_mfma_f32_16x16x32_bf16(afrag[kb], bfrag[0][kb], acc0, 0, 0, 0);
      acc1 = __builtin_amdgcn_mfma_f32_16x16x32_bf16(afrag[kb], bfrag[1][kb], acc1, 0, 0, 0);
    }
    // store: row = m0 + quad*4 + r, col = wv*32 + t*16 + lr
#pragma unroll
    for (int t = 0; t < 2; ++t) {
      const f32x4 a = t ? acc1 : acc0;
      int col = wv * 32 + t * 16 + lr;
#pragma unroll
      for (int r = 0; r < 4; ++r) {
        size_t oi = (size_t)(m0 + quad * 4 + r) * HC + col;
        float val = a[r];
        if (mat == 0)      qb[oi] = f2bf(val);
        else if (mat == 1) kv16[2 * oi] = f2bf(val);        // k -> low16
        else if (mat == 2) kv16[2 * oi + 1] = f2bf(val);    // v -> high16
        else {
          if (ISBF) ((unsigned short*)out)[oi] = f2bf(val);
          else      ((float*)out)[oi] = val;
        }
      }
    }
  }
}

__global__ __launch_bounds__(256) void k_qkvs(const void* __restrict__ x,
    const void* __restrict__ Wq, const void* __restrict__ Wk,
    const void* __restrict__ Wv, const void* __restrict__ Ws,
    const int* __restrict__ flag, unsigned short* __restrict__ qb,
    unsigned* __restrict__ kvb, void* __restrict__ out) {
  __shared__ unsigned short wt[HC * WT_STRIDE];   // ~34 KB
  int mat = blockIdx.x / QBLK;
  int mc  = blockIdx.x % QBLK;
  const void* W = (mat == 0) ? Wq : (mat == 1) ? Wk : (mat == 2) ? Wv : Ws;
  if (flag[1]) qkvs_mfma_body<1>(x, W, mat, mc, qb, (unsigned short*)kvb, out, wt);
  else         qkvs_mfma_body<0>(x, W, mat, mc, qb, (unsigned short*)kvb, out, wt);
}

// ---- counting sort by dst ----------------------------------------------------
__global__ __launch_bounds__(256) void k_hist(const void* __restrict__ eidx,
                                              const int* __restrict__ flag,
                                              int* __restrict__ hist) {
  int e = blockIdx.x * 256 + threadIdx.x;
  if (e >= NE) return;
  int dst = idx_at(eidx, (long long)NE + e, flag[0]);
  dst = min(max(dst, 0), NN - 1);
  atomicAdd(&hist[dst], 1);
}

// two-level scan: block sums -> scan sums -> local scan + offset
__global__ __launch_bounds__(256) void k_scan1(const int* __restrict__ hist,
                                               int* __restrict__ bsum) {
  __shared__ int red[4];
  int i = blockIdx.x * 256 + threadIdx.x;
  int v = (i < NN) ? hist[i] : 0;
#pragma unroll
  for (int m = 1; m < 64; m <<= 1) v += __shfl_xor(v, m);
  if ((threadIdx.x & 63) == 0) red[threadIdx.x >> 6] = v;
  __syncthreads();
  if (threadIdx.x == 0) bsum[blockIdx.x] = red[0] + red[1] + red[2] + red[3];
}

__global__ __launch_bounds__(256) void k_scan2(const int* __restrict__ bsum,
                                               int* __restrict__ bexc) {
  __shared__ int s[256];
  int t = threadIdx.x;
  int v = (t < NBLK) ? bsum[t] : 0;
  s[t] = v;
  __syncthreads();
  for (int off = 1; off < 256; off <<= 1) {
    int u = (t >= off) ? s[t - off] : 0;
    __syncthreads();
    s[t] += u;
    __syncthreads();
  }
  if (t < NBLK) bexc[t] = s[t] - v;
}

__global__ __launch_bounds__(256) void k_scan3(const int* __restrict__ hist,
    const int* __restrict__ bexc, int* __restrict__ rowptr,
    int* __restrict__ cursor) {
  __shared__ int s[256];
  int t = threadIdx.x;
  int i = blockIdx.x * 256 + t;
  int v = (i < NN) ? hist[i] : 0;
  s[t] = v;
  __syncthreads();
  for (int off = 1; off < 256; off <<= 1) {
    int u = (t >= off) ? s[t - off] : 0;
    __syncthreads();
    s[t] += u;
    __syncthreads();
  }
  int excl = bexc[blockIdx.x] + s[t] - v;
  if (i < NN) { rowptr[i] = excl; cursor[i] = excl; }  // cursor aliases hist: block-local RAW, safe
  if (i == 0) rowptr[NN] = NE;   // all edges binned (dst clamped)
}

// scatter packed (src<<3 | et) into dst-sorted order
__global__ __launch_bounds__(256) void k_scatter(const void* __restrict__ eidx,
    const void* __restrict__ etype, const int* __restrict__ flag,
    int* __restrict__ cursor, int* __restrict__ srcet) {
  int e = blockIdx.x * 256 + threadIdx.x;
  if (e >= NE) return;
  const int is64 = flag[0];
  int src = idx_at(eidx, e, is64);
  int dst = idx_at(eidx, (long long)NE + e, is64);
  int et  = idx_at(etype, e, is64);
  src = min(max(src, 0), NN - 1);
  dst = min(max(dst, 0), NN - 1);
  et  = min(max(et, 0), NR - 1);
  int pos = atomicAdd(&cursor[dst], 1);
  srcet[pos] = (src << 3) | et;
}

// ---- fused attention+gather: logits via lane-split + shuffle reduce,
// single loop accumulates denom and message; out = msg/denom + skip ----------
__global__ __launch_bounds__(256) void k_gather(const int* __restrict__ rowptr,
    const int* __restrict__ srcet, const unsigned short* __restrict__ qb,
    const unsigned* __restrict__ kvb, const float* __restrict__ ee,
    const int* __restrict__ flag, void* __restrict__ out) {
  int n = blockIdx.x * 2 + (threadIdx.x >> 7);   // wave-uniform
  int j = threadIdx.x & 127;                      // channel; head = j>>5
  int beg = __builtin_amdgcn_readfirstlane(rowptr[n]);
  int end = __builtin_amdgcn_readfirstlane(rowptr[n + 1]);
  float qj = __uint_as_float(((unsigned)qb[(size_t)n * HC + j]) << 16);
  const float sc = 0.17677669529663687f;  // 1/sqrt(32)
  float dn = 0.f, acc = 0.f;
  int p = beg;
  for (; p + 2 <= end; p += 2) {
    int se0 = srcet[p], se1 = srcet[p + 1];
    unsigned u0 = kvb[(size_t)(se0 >> 3) * HC + j];
    unsigned u1 = kvb[(size_t)(se1 >> 3) * HC + j];
    float e0 = ee[((se0 & 7) << 7) + j];
    float e1 = ee[((se1 & 7) << 7) + j];
    float p0 = qj * (bflo(u0) + e0);
    float p1 = qj * (bflo(u1) + e1);
    p0 += __shfl_xor(p0, 1);  p1 += __shfl_xor(p1, 1);
    p0 += __shfl_xor(p0, 2);  p1 += __shfl_xor(p1, 2);
    p0 += __shfl_xor(p0, 4);  p1 += __shfl_xor(p1, 4);
    p0 += __shfl_xor(p0, 8);  p1 += __shfl_xor(p1, 8);
    p0 += __shfl_xor(p0, 16); p1 += __shfl_xor(p1, 16);
    float x0 = __expf(p0 * sc), x1 = __expf(p1 * sc);
    dn += x0 + x1;
    acc += (bfhi(u0) + e0) * x0 + (bfhi(u1) + e1) * x1;
  }
  if (p < end) {
    int se0 = srcet[p];
    unsigned u0 = kvb[(size_t)(se0 >> 3) * HC + j];
    float e0 = ee[((se0 & 7) << 7) + j];
    float p0 = qj * (bflo(u0) + e0);
    p0 += __shfl_xor(p0, 1);
    p0 += __shfl_xor(p0, 2);
    p0 += __shfl_xor(p0, 4);
    p0 += __shfl_xor(p0, 8);
    p0 += __shfl_xor(p0, 16);
    float x0 = __expf(p0 * sc);
    dn += x0;
    acc += (bfhi(u0) + e0) * x0;
  }
  float o = acc / (dn + 1e-16f);
  size_t oi = (size_t)n * HC + j;
  if (flag[1]) {  // skip was stored dtype-matched in d_out; same-thread RAW, safe
    o += __uint_as_float(((unsigned)((const unsigned short*)out)[oi]) << 16);
    ((unsigned short*)out)[oi] = f2bf(o);
  } else {
    o += ((const float*)out)[oi];
    ((float*)out)[oi] = o;
  }
}

// ---- launch -----------------------------------------------------------------
extern "C" void kernel_launch(void* const* d_in, const int* in_sizes, int n_in,
                              void* d_out, int out_size, void* d_ws, size_t ws_size,
                              hipStream_t stream) {
  const void* x     = d_in[0];
  const void* eidx  = d_in[1];   // [2,E]: first E = src, next E = dst
  const void* etype = d_in[2];
  const void* emb   = d_in[3];
  const void* Wq    = d_in[4];
  const void* Wk    = d_in[5];
  const void* Wv    = d_in[6];
  const void* We    = d_in[7];
  const void* Ws    = d_in[8];

  // workspace layout (float units) — total ~42.0 MB (< proven-safe 48.4 MB)
  float* base   = (float*)d_ws;
  int*   flag   = (int*)base;                       // 16
  float* ee     = base + 16;                        // 1024 -> 1040
  int*   rowptr = (int*)(base + 1040);              // 50001 -> pad 50004
  int*   cursor = (int*)(base + 51044);             // 50000 (doubles as hist)
  int*   bsum   = (int*)(base + 101044);            // 196 -> pad 256
  int*   bexc   = (int*)(base + 101300);            // 196 -> pad 268 (align 16)
  int*   srcet  = (int*)(base + 101568);            // NE -> 901568
  unsigned short* qb  = (unsigned short*)(base + 901568);   // NN*HC bf16 (3.2M fl)
  unsigned*       kvb = (unsigned*)(base + 4101568);        // NN*HC uint (6.4M fl)
  // end: 10501568 floats = 42.0 MB

  k_prep   <<<NBLK + 1, 256, 0, stream>>>((const int*)eidx, (const unsigned*)x,
                                          emb, We, flag, cursor, ee);
  k_qkvs   <<<4 * QBLK, 256, 0, stream>>>(x, Wq, Wk, Wv, Ws, flag, qb, kvb, d_out);
  k_hist   <<<NE / 256, 256, 0, stream>>>(eidx, flag, cursor);
  k_scan1  <<<NBLK, 256, 0, stream>>>(cursor, bsum);
  k_scan2  <<<1, 256, 0, stream>>>(bsum, bexc);
  k_scan3  <<<NBLK, 256, 0, stream>>>(cursor, bexc, rowptr, cursor);
  k_scatter<<<NE / 256, 256, 0, stream>>>(eidx, etype, flag, cursor, srcet);
  k_gather <<<NN / 2, 256, 0, stream>>>(rowptr, srcet, qb, kvb, ee, flag, d_out);
}

// Round 7
// 314.949 us; speedup vs baseline: 18.2599x; 1.1432x over previous
//
#include <hip/hip_runtime.h>
#include <hip/hip_bf16.h>

// Problem constants (from reference):
#define NN 50000   // nodes
#define FF 128     // in channels
#define NH 4       // heads
#define CH 32      // channels/head
#define HC 128     // NH*CH
#define NE 800000  // edges
#define NR 8       // relations
#define DEDIM 64   // edge emb dim
#define NBLK 196   // ceil(NN/256)
#define HBLK 3125  // NE/256
#define QBLK 200   // M-chunk blocks per matrix in qkvs
#define MTILES 3125 // NN/16

typedef __hip_bfloat16 bf16;
typedef __attribute__((ext_vector_type(8))) short short8;   // 8 x bf16 (4 VGPR)
typedef __attribute__((ext_vector_type(4))) float f32x4;

// ---- helpers ----------------------------------------------------------------
__device__ __forceinline__ float bflo(unsigned u) { return __uint_as_float(u << 16); }
__device__ __forceinline__ float bfhi(unsigned u) { return __uint_as_float(u & 0xFFFF0000u); }

__device__ __forceinline__ unsigned short f2bf(float f) {
  unsigned u = __float_as_uint(f);
  unsigned r = (u + 0x7FFFu + ((u >> 16) & 1u)) >> 16;  // round-nearest-even
  return (unsigned short)r;
}
__device__ __forceinline__ unsigned pack2bf(float lo, float hi) {
  return (unsigned)f2bf(lo) | ((unsigned)f2bf(hi) << 16);
}

template <int ISBF>
__device__ __forceinline__ float ldf(const void* p, size_t i) {
  if (ISBF) return __bfloat162float(((const bf16*)p)[i]);
  return ((const float*)p)[i];
}

__device__ __forceinline__ int idx_at(const void* p, long long i, int is64) {
  if (is64) { long long v = ((const long long*)p)[i]; return (int)v; }
  return ((const int*)p)[i];
}

// ---- prep: hist (blocks 0..HBLK-1, self-detecting is64) + detect/ee (last) --
// flag[0]: 1 if edge_index is int64; flag[1]: 1 if float inputs are bf16
// hist must be pre-zeroed (hipMemsetAsync in kernel_launch).
__global__ __launch_bounds__(256) void k_prep(const int* __restrict__ eidx32,
    const unsigned* __restrict__ xw, const void* __restrict__ emb,
    const void* __restrict__ We, int* __restrict__ flag,
    int* __restrict__ hist, float* __restrict__ ee) {
  if (blockIdx.x < HBLK) {
    // wave-local int64 detection: 64 distinct hi-word samples per wave
    unsigned long long b = __ballot(eidx32[2 * (threadIdx.x & 127) + 1] != 0);
    int is64 = (b == 0ULL);
    int e = blockIdx.x * 256 + threadIdx.x;   // always < NE (HBLK*256 == NE)
    int dst = idx_at(eidx32, (long long)NE + e, is64);
    dst = min(max(dst, 0), NN - 1);
    atomicAdd(&hist[dst], 1);
    return;
  }
  __shared__ int nzIdx, badBf;
  __shared__ float es[NR * DEDIM];
  if (threadIdx.x == 0) { nzIdx = 0; badBf = 0; }
  __syncthreads();
  if (threadIdx.x < 128) {
    if (eidx32[2 * threadIdx.x + 1] != 0) atomicAdd(&nzIdx, 1);
    unsigned e = (xw[threadIdx.x] >> 7) & 0xFFu;  // exponent of low-half bf16
    if (e < 90u || e > 140u) atomicAdd(&badBf, 1);
  }
  __syncthreads();
  const int isbf = (badBf == 0);
  if (threadIdx.x == 0) { flag[0] = (nzIdx == 0); flag[1] = isbf; }
  for (int i = threadIdx.x; i < NR * DEDIM; i += 256)
    es[i] = isbf ? ldf<1>(emb, i) : ldf<0>(emb, i);
  __syncthreads();
  for (int o = threadIdx.x; o < NR * HC; o += 256) {
    int r = o >> 7, j = o & 127;
    float acc = 0.f;
    if (isbf) { for (int d = 0; d < DEDIM; ++d) acc += es[r * DEDIM + d] * ldf<1>(We, d * HC + j); }
    else      { for (int d = 0; d < DEDIM; ++d) acc += es[r * DEDIM + d] * ldf<0>(We, d * HC + j); }
    ee[o] = acc;
  }
}

// ---- MFMA projection: grid = 4 matrices x QBLK chunks (unchanged) -----------
#define WT_STRIDE 136   // bf16 elems; 272 B rows: 16B-aligned, 2-way max bank alias

template <int ISBF>
__device__ __forceinline__ void qkvs_mfma_body(const void* __restrict__ x,
    const void* __restrict__ W, int mat, int mc,
    unsigned short* __restrict__ qb, unsigned short* __restrict__ kv16,
    void* __restrict__ out, unsigned short* wt) {
  for (int i = threadIdx.x; i < FF * HC; i += 256) {
    int k = i >> 7, n = i & 127;
    unsigned short v = ISBF ? ((const unsigned short*)W)[i]
                            : f2bf(((const float*)W)[i]);
    wt[n * WT_STRIDE + k] = v;
  }
  __syncthreads();
  const int lane = threadIdx.x & 63;
  const int wv   = threadIdx.x >> 6;
  const int quad = lane >> 4;
  const int lr   = lane & 15;
  short8 bfrag[2][4];
#pragma unroll
  for (int t = 0; t < 2; ++t) {
    int ncol = wv * 32 + t * 16 + lr;
#pragma unroll
    for (int kb = 0; kb < 4; ++kb)
      bfrag[t][kb] = *(const short8*)&wt[ncol * WT_STRIDE + kb * 32 + quad * 8];
  }
  const unsigned short* xu = (const unsigned short*)x;
  const float* xf = (const float*)x;
  for (int mt = mc; mt < MTILES; mt += QBLK) {
    int m0 = mt * 16;
    short8 afrag[4];
#pragma unroll
    for (int kb = 0; kb < 4; ++kb) {
      size_t off = (size_t)(m0 + lr) * FF + kb * 32 + quad * 8;
      if (ISBF) {
        afrag[kb] = *(const short8*)(xu + off);
      } else {
        float4 fa = *(const float4*)(xf + off);
        float4 fb = *(const float4*)(xf + off + 4);
        short8 a;
        a[0] = (short)f2bf(fa.x); a[1] = (short)f2bf(fa.y);
        a[2] = (short)f2bf(fa.z); a[3] = (short)f2bf(fa.w);
        a[4] = (short)f2bf(fb.x); a[5] = (short)f2bf(fb.y);
        a[6] = (short)f2bf(fb.z); a[7] = (short)f2bf(fb.w);
        afrag[kb] = a;
      }
    }
    f32x4 acc0 = {0.f, 0.f, 0.f, 0.f}, acc1 = {0.f, 0.f, 0.f, 0.f};
#pragma unroll
    for (int kb = 0; kb < 4; ++kb) {
      acc0 = __builtin_amdgcn_mfma_f32_16x16x32_bf16(afrag[kb], bfrag[0][kb], acc0, 0, 0, 0);
      acc1 = __builtin_amdgcn_mfma_f32_16x16x32_bf16(afrag[kb], bfrag[1][kb], acc1, 0, 0, 0);
    }
#pragma unroll
    for (int t = 0; t < 2; ++t) {
      const f32x4 a = t ? acc1 : acc0;
      int col = wv * 32 + t * 16 + lr;
#pragma unroll
      for (int r = 0; r < 4; ++r) {
        size_t oi = (size_t)(m0 + quad * 4 + r) * HC + col;
        float val = a[r];
        if (mat == 0)      qb[oi] = f2bf(val);
        else if (mat == 1) kv16[2 * oi] = f2bf(val);        // k -> low16
        else if (mat == 2) kv16[2 * oi + 1] = f2bf(val);    // v -> high16
        else {
          if (ISBF) ((unsigned short*)out)[oi] = f2bf(val);
          else      ((float*)out)[oi] = val;
        }
      }
    }
  }
}

__global__ __launch_bounds__(256) void k_qkvs(const void* __restrict__ x,
    const void* __restrict__ Wq, const void* __restrict__ Wk,
    const void* __restrict__ Wv, const void* __restrict__ Ws,
    const int* __restrict__ flag, unsigned short* __restrict__ qb,
    unsigned* __restrict__ kvb, void* __restrict__ out) {
  __shared__ unsigned short wt[HC * WT_STRIDE];   // ~34 KB
  int mat = blockIdx.x / QBLK;
  int mc  = blockIdx.x % QBLK;
  const void* W = (mat == 0) ? Wq : (mat == 1) ? Wk : (mat == 2) ? Wv : Ws;
  if (flag[1]) qkvs_mfma_body<1>(x, W, mat, mc, qb, (unsigned short*)kvb, out, wt);
  else         qkvs_mfma_body<0>(x, W, mat, mc, qb, (unsigned short*)kvb, out, wt);
}

// ---- scan: block sums (scan1), then per-block scan with inline top scan ------
__global__ __launch_bounds__(256) void k_scan1(const int* __restrict__ hist,
                                               int* __restrict__ bsum) {
  __shared__ int red[4];
  int i = blockIdx.x * 256 + threadIdx.x;
  int v = (i < NN) ? hist[i] : 0;
#pragma unroll
  for (int m = 1; m < 64; m <<= 1) v += __shfl_xor(v, m);
  if ((threadIdx.x & 63) == 0) red[threadIdx.x >> 6] = v;
  __syncthreads();
  if (threadIdx.x == 0) bsum[blockIdx.x] = red[0] + red[1] + red[2] + red[3];
}

// each block: scan the 196 block sums locally (L2-hot) + local 256-scan
__global__ __launch_bounds__(256) void k_scan13(const int* __restrict__ hist,
    const int* __restrict__ bsum, int* __restrict__ rowptr,
    int* __restrict__ cursor) {
  __shared__ int s[256];
  int t = threadIdx.x;
  // phase 1: scan block sums, get this block's exclusive offset
  int bv = (t < NBLK) ? bsum[t] : 0;
  s[t] = bv;
  __syncthreads();
  for (int off = 1; off < 256; off <<= 1) {
    int u = (t >= off) ? s[t - off] : 0;
    __syncthreads();
    s[t] += u;
    __syncthreads();
  }
  int bexc = (blockIdx.x == 0) ? 0 : s[blockIdx.x - 1];  // uniform
  __syncthreads();
  // phase 2: local scan of this block's hist chunk
  int i = blockIdx.x * 256 + t;
  int v = (i < NN) ? hist[i] : 0;
  s[t] = v;
  __syncthreads();
  for (int off = 1; off < 256; off <<= 1) {
    int u = (t >= off) ? s[t - off] : 0;
    __syncthreads();
    s[t] += u;
    __syncthreads();
  }
  int excl = bexc + s[t] - v;
  if (i < NN) { rowptr[i] = excl; cursor[i] = excl; }  // cursor aliases hist: block-local RAW, safe
  if (i == 0) rowptr[NN] = NE;   // all edges binned (dst clamped)
}

// scatter packed (src<<3 | et) into dst-sorted order
__global__ __launch_bounds__(256) void k_scatter(const void* __restrict__ eidx,
    const void* __restrict__ etype, const int* __restrict__ flag,
    int* __restrict__ cursor, int* __restrict__ srcet) {
  int e = blockIdx.x * 256 + threadIdx.x;
  if (e >= NE) return;
  const int is64 = flag[0];
  int src = idx_at(eidx, e, is64);
  int dst = idx_at(eidx, (long long)NE + e, is64);
  int et  = idx_at(etype, e, is64);
  src = min(max(src, 0), NN - 1);
  dst = min(max(dst, 0), NN - 1);
  et  = min(max(et, 0), NR - 1);
  int pos = atomicAdd(&cursor[dst], 1);
  srcet[pos] = (src << 3) | et;
}

// ---- fused attention+gather: 1 wave/node, 2 channels/lane, unroll-4 ---------
// lane l: head h = l>>4, channel pair j0 = 32h + 2*(l&15), j0+1
__global__ __launch_bounds__(256) void k_gather(const int* __restrict__ rowptr,
    const int* __restrict__ srcet, const unsigned short* __restrict__ qb,
    const unsigned* __restrict__ kvb, const float* __restrict__ ee,
    const int* __restrict__ flag, void* __restrict__ out) {
  int n = blockIdx.x * 4 + (threadIdx.x >> 6);   // wave-uniform node
  int l = threadIdx.x & 63;
  int j0 = ((l >> 4) << 5) + ((l & 15) << 1);    // channel pair base
  int beg = __builtin_amdgcn_readfirstlane(rowptr[n]);
  int end = __builtin_amdgcn_readfirstlane(rowptr[n + 1]);
  unsigned qp = *(const unsigned*)(qb + (size_t)n * HC + j0);
  float q0 = bflo(qp), q1 = bfhi(qp);
  const float sc = 0.17677669529663687f;  // 1/sqrt(32)
  float dn = 0.f, a0 = 0.f, a1 = 0.f;
  int p = beg;
  for (; p + 4 <= end; p += 4) {
    int se[4];
    uint2 kv[4];
    float2 ev[4];
#pragma unroll
    for (int t = 0; t < 4; ++t) se[t] = srcet[p + t];         // s_load_dwordx4
#pragma unroll
    for (int t = 0; t < 4; ++t)
      kv[t] = *(const uint2*)(kvb + (size_t)(se[t] >> 3) * HC + j0);
#pragma unroll
    for (int t = 0; t < 4; ++t)
      ev[t] = *(const float2*)(ee + ((se[t] & 7) << 7) + j0);
#pragma unroll
    for (int t = 0; t < 4; ++t) {
      float k0 = bflo(kv[t].x) + ev[t].x;
      float k1 = bflo(kv[t].y) + ev[t].y;
      float pp = q0 * k0 + q1 * k1;
      pp += __shfl_xor(pp, 1);
      pp += __shfl_xor(pp, 2);
      pp += __shfl_xor(pp, 4);
      pp += __shfl_xor(pp, 8);
      float xx = __expf(pp * sc);
      dn += xx;
      a0 += (bfhi(kv[t].x) + ev[t].x) * xx;
      a1 += (bfhi(kv[t].y) + ev[t].y) * xx;
    }
  }
  for (; p < end; ++p) {
    int se0 = srcet[p];
    uint2 kv0 = *(const uint2*)(kvb + (size_t)(se0 >> 3) * HC + j0);
    float2 ev0 = *(const float2*)(ee + ((se0 & 7) << 7) + j0);
    float k0 = bflo(kv0.x) + ev0.x;
    float k1 = bflo(kv0.y) + ev0.y;
    float pp = q0 * k0 + q1 * k1;
    pp += __shfl_xor(pp, 1);
    pp += __shfl_xor(pp, 2);
    pp += __shfl_xor(pp, 4);
    pp += __shfl_xor(pp, 8);
    float xx = __expf(pp * sc);
    dn += xx;
    a0 += (bfhi(kv0.x) + ev0.x) * xx;
    a1 += (bfhi(kv0.y) + ev0.y) * xx;
  }
  float inv = 1.f / (dn + 1e-16f);
  float o0 = a0 * inv, o1 = a1 * inv;
  size_t oi = (size_t)n * HC + j0;
  if (flag[1]) {  // skip was stored dtype-matched in d_out; same-thread RAW, safe
    unsigned sk = *(const unsigned*)((const unsigned short*)out + oi);
    o0 += bflo(sk);
    o1 += bfhi(sk);
    *(unsigned*)((unsigned short*)out + oi) = pack2bf(o0, o1);
  } else {
    float2 sk = *(const float2*)((const float*)out + oi);
    float2 ov = make_float2(o0 + sk.x, o1 + sk.y);
    *(float2*)((float*)out + oi) = ov;
  }
}

// ---- launch -----------------------------------------------------------------
extern "C" void kernel_launch(void* const* d_in, const int* in_sizes, int n_in,
                              void* d_out, int out_size, void* d_ws, size_t ws_size,
                              hipStream_t stream) {
  const void* x     = d_in[0];
  const void* eidx  = d_in[1];   // [2,E]: first E = src, next E = dst
  const void* etype = d_in[2];
  const void* emb   = d_in[3];
  const void* Wq    = d_in[4];
  const void* Wk    = d_in[5];
  const void* Wv    = d_in[6];
  const void* We    = d_in[7];
  const void* Ws    = d_in[8];

  // workspace layout (float units) — total ~42.0 MB (< proven-safe 48.4 MB)
  float* base   = (float*)d_ws;
  int*   flag   = (int*)base;                       // 16
  float* ee     = base + 16;                        // 1024 -> 1040
  int*   rowptr = (int*)(base + 1040);              // 50001 -> pad 50004
  int*   cursor = (int*)(base + 51044);             // 50000 (doubles as hist)
  int*   bsum   = (int*)(base + 101044);            // 196 -> pad 256
  int*   srcet  = (int*)(base + 101568);            // NE -> 901568
  unsigned short* qb  = (unsigned short*)(base + 901568);   // NN*HC bf16 (3.2M fl)
  unsigned*       kvb = (unsigned*)(base + 4101568);        // NN*HC uint (6.4M fl)
  // end: 10501568 floats = 42.0 MB

  hipMemsetAsync(cursor, 0, NN * sizeof(int), stream);   // hist zero (capture-safe)
  k_prep   <<<HBLK + 1, 256, 0, stream>>>((const int*)eidx, (const unsigned*)x,
                                          emb, We, flag, cursor, ee);
  k_qkvs   <<<4 * QBLK, 256, 0, stream>>>(x, Wq, Wk, Wv, Ws, flag, qb, kvb, d_out);
  k_scan1  <<<NBLK, 256, 0, stream>>>(cursor, bsum);
  k_scan13 <<<NBLK, 256, 0, stream>>>(cursor, bsum, rowptr, cursor);
  k_scatter<<<HBLK, 256, 0, stream>>>(eidx, etype, flag, cursor, srcet);
  k_gather <<<NN / 4, 256, 0, stream>>>(rowptr, srcet, qb, kvb, ee, flag, d_out);
}

// Round 8
// 295.197 us; speedup vs baseline: 19.4817x; 1.0669x over previous
//
#include <hip/hip_runtime.h>
#include <hip/hip_bf16.h>

// Problem constants (from reference):
#define NN 50000   // nodes
#define FF 128     // in channels
#define NH 4       // heads
#define CH 32      // channels/head
#define HC 128     // NH*CH
#define NE 800000  // edges
#define NR 8       // relations
#define DEDIM 64   // edge emb dim
#define NBLK 196   // ceil(NN/256)
#define HBLK 3125  // NE/256
#define QBLK 250   // M-chunk blocks per group in qkvs
#define MTILES 3125 // NN/16

typedef __hip_bfloat16 bf16;
typedef __attribute__((ext_vector_type(8))) short short8;   // 8 x bf16 (4 VGPR)
typedef __attribute__((ext_vector_type(4))) float f32x4;

// ---- helpers ----------------------------------------------------------------
__device__ __forceinline__ float bflo(unsigned u) { return __uint_as_float(u << 16); }
__device__ __forceinline__ float bfhi(unsigned u) { return __uint_as_float(u & 0xFFFF0000u); }

__device__ __forceinline__ unsigned short f2bf(float f) {
  unsigned u = __float_as_uint(f);
  unsigned r = (u + 0x7FFFu + ((u >> 16) & 1u)) >> 16;  // round-nearest-even
  return (unsigned short)r;
}
__device__ __forceinline__ unsigned pack2bf(float lo, float hi) {
  return (unsigned)f2bf(lo) | ((unsigned)f2bf(hi) << 16);
}

template <int ISBF>
__device__ __forceinline__ float ldf(const void* p, size_t i) {
  if (ISBF) return __bfloat162float(((const bf16*)p)[i]);
  return ((const float*)p)[i];
}

__device__ __forceinline__ int idx_at(const void* p, long long i, int is64) {
  if (is64) { long long v = ((const long long*)p)[i]; return (int)v; }
  return ((const int*)p)[i];
}

// ---- prep: hist + packed dst/srcet side arrays (blocks 0..HBLK-1),
//      detect + ee (last block). hist pre-zeroed via hipMemsetAsync. ----------
// flag[0]: 1 if edge_index is int64; flag[1]: 1 if float inputs are bf16
__global__ __launch_bounds__(256) void k_prep(const int* __restrict__ eidx32,
    const void* __restrict__ etype, const unsigned* __restrict__ xw,
    const void* __restrict__ emb, const void* __restrict__ We,
    int* __restrict__ flag, int* __restrict__ hist, float* __restrict__ ee,
    int* __restrict__ dstp, int* __restrict__ setp) {
  if (blockIdx.x < HBLK) {
    // wave-local int64 detection: 64 distinct hi-word samples per wave
    unsigned long long b = __ballot(eidx32[2 * (threadIdx.x & 127) + 1] != 0);
    int is64 = (b == 0ULL);
    int e = blockIdx.x * 256 + threadIdx.x;   // always < NE (HBLK*256 == NE)
    int src = idx_at(eidx32, e, is64);
    int dst = idx_at(eidx32, (long long)NE + e, is64);
    int et  = idx_at(etype, e, is64);
    src = min(max(src, 0), NN - 1);
    dst = min(max(dst, 0), NN - 1);
    et  = min(max(et, 0), NR - 1);
    dstp[e] = dst;
    setp[e] = (src << 3) | et;
    atomicAdd(&hist[dst], 1);
    return;
  }
  __shared__ int nzIdx, badBf;
  __shared__ float es[NR * DEDIM];
  if (threadIdx.x == 0) { nzIdx = 0; badBf = 0; }
  __syncthreads();
  if (threadIdx.x < 128) {
    if (eidx32[2 * threadIdx.x + 1] != 0) atomicAdd(&nzIdx, 1);
    unsigned e = (xw[threadIdx.x] >> 7) & 0xFFu;  // exponent of low-half bf16
    if (e < 90u || e > 140u) atomicAdd(&badBf, 1);
  }
  __syncthreads();
  const int isbf = (badBf == 0);
  if (threadIdx.x == 0) { flag[0] = (nzIdx == 0); flag[1] = isbf; }
  for (int i = threadIdx.x; i < NR * DEDIM; i += 256)
    es[i] = isbf ? ldf<1>(emb, i) : ldf<0>(emb, i);
  __syncthreads();
  for (int o = threadIdx.x; o < NR * HC; o += 256) {
    int r = o >> 7, j = o & 127;
    float acc = 0.f;
    if (isbf) { for (int d = 0; d < DEDIM; ++d) acc += es[r * DEDIM + d] * ldf<1>(We, d * HC + j); }
    else      { for (int d = 0; d < DEDIM; ++d) acc += es[r * DEDIM + d] * ldf<0>(We, d * HC + j); }
    ee[o] = acc;
  }
}

// ---- MFMA projection, 2 fused groups: grp0 = q+skip, grp1 = k+v packed ------
// Both weight matrices pass through the same LDS buffer sequentially; each
// A-fragment feeds 16 MFMAs; kv stores are full 32-bit words (no partial
// sectors, no RMW).
#define WT_STRIDE 136   // bf16 elems; 272 B rows: 16B-aligned, 2-way max bank alias

template <int ISBF>
__device__ __forceinline__ void stage_w(const void* __restrict__ W,
                                        unsigned short* __restrict__ wt) {
  for (int i = threadIdx.x; i < FF * HC; i += 256) {
    int k = i >> 7, n = i & 127;
    wt[n * WT_STRIDE + k] = ISBF ? ((const unsigned short*)W)[i]
                                 : f2bf(((const float*)W)[i]);
  }
}

__device__ __forceinline__ void hoist_b(const unsigned short* __restrict__ wt,
                                        int wv, int quad, int lr,
                                        short8 bf[2][4]) {
#pragma unroll
  for (int t = 0; t < 2; ++t) {
    int ncol = wv * 32 + t * 16 + lr;
#pragma unroll
    for (int kb = 0; kb < 4; ++kb)
      bf[t][kb] = *(const short8*)&wt[ncol * WT_STRIDE + kb * 32 + quad * 8];
  }
}

template <int ISBF>
__device__ __forceinline__ void qkvs_body(const void* __restrict__ x,
    const void* __restrict__ W0, const void* __restrict__ W1, int grp, int mc,
    unsigned short* __restrict__ qb, unsigned* __restrict__ kvb,
    void* __restrict__ out, unsigned short* wt) {
  const int lane = threadIdx.x & 63;
  const int wv   = threadIdx.x >> 6;
  const int quad = lane >> 4;
  const int lr   = lane & 15;
  short8 bf0[2][4], bf1[2][4];
  stage_w<ISBF>(W0, wt);
  __syncthreads();
  hoist_b(wt, wv, quad, lr, bf0);
  __syncthreads();           // all reads of W0 done before overwrite
  stage_w<ISBF>(W1, wt);
  __syncthreads();
  hoist_b(wt, wv, quad, lr, bf1);
  const unsigned short* xu = (const unsigned short*)x;
  const float* xf = (const float*)x;
  for (int mt = mc; mt < MTILES; mt += QBLK) {
    int m0 = mt * 16;
    short8 af[4];
#pragma unroll
    for (int kb = 0; kb < 4; ++kb) {
      size_t off = (size_t)(m0 + lr) * FF + kb * 32 + quad * 8;
      if (ISBF) {
        af[kb] = *(const short8*)(xu + off);
      } else {
        float4 fa = *(const float4*)(xf + off);
        float4 fb = *(const float4*)(xf + off + 4);
        short8 a;
        a[0] = (short)f2bf(fa.x); a[1] = (short)f2bf(fa.y);
        a[2] = (short)f2bf(fa.z); a[3] = (short)f2bf(fa.w);
        a[4] = (short)f2bf(fb.x); a[5] = (short)f2bf(fb.y);
        a[6] = (short)f2bf(fb.z); a[7] = (short)f2bf(fb.w);
        af[kb] = a;
      }
    }
    f32x4 a00 = {0.f, 0.f, 0.f, 0.f}, a01 = {0.f, 0.f, 0.f, 0.f};
    f32x4 a10 = {0.f, 0.f, 0.f, 0.f}, a11 = {0.f, 0.f, 0.f, 0.f};
#pragma unroll
    for (int kb = 0; kb < 4; ++kb) {
      a00 = __builtin_amdgcn_mfma_f32_16x16x32_bf16(af[kb], bf0[0][kb], a00, 0, 0, 0);
      a01 = __builtin_amdgcn_mfma_f32_16x16x32_bf16(af[kb], bf0[1][kb], a01, 0, 0, 0);
      a10 = __builtin_amdgcn_mfma_f32_16x16x32_bf16(af[kb], bf1[0][kb], a10, 0, 0, 0);
      a11 = __builtin_amdgcn_mfma_f32_16x16x32_bf16(af[kb], bf1[1][kb], a11, 0, 0, 0);
    }
#pragma unroll
    for (int t = 0; t < 2; ++t) {
      const f32x4 v0 = t ? a01 : a00;   // mat0: q or k
      const f32x4 v1 = t ? a11 : a10;   // mat1: skip or v
      int col = wv * 32 + t * 16 + lr;
#pragma unroll
      for (int r = 0; r < 4; ++r) {
        size_t oi = (size_t)(m0 + quad * 4 + r) * HC + col;
        if (grp == 0) {
          qb[oi] = f2bf(v0[r]);
          if (ISBF) ((unsigned short*)out)[oi] = f2bf(v1[r]);
          else      ((float*)out)[oi] = v1[r];
        } else {
          kvb[oi] = pack2bf(v0[r], v1[r]);   // k low16, v high16
        }
      }
    }
  }
}

__global__ __launch_bounds__(256) void k_qkvs(const void* __restrict__ x,
    const void* __restrict__ Wq, const void* __restrict__ Wk,
    const void* __restrict__ Wv, const void* __restrict__ Ws,
    const int* __restrict__ flag, unsigned short* __restrict__ qb,
    unsigned* __restrict__ kvb, void* __restrict__ out) {
  __shared__ unsigned short wt[HC * WT_STRIDE];   // ~34 KB
  int grp = blockIdx.x / QBLK;   // 0: q+skip, 1: k+v
  int mc  = blockIdx.x % QBLK;
  const void* W0 = grp ? Wk : Wq;
  const void* W1 = grp ? Wv : Ws;
  if (flag[1]) qkvs_body<1>(x, W0, W1, grp, mc, qb, kvb, out, wt);
  else         qkvs_body<0>(x, W0, W1, grp, mc, qb, kvb, out, wt);
}

// ---- scan: block sums (scan1), then per-block scan with inline top scan ------
__global__ __launch_bounds__(256) void k_scan1(const int* __restrict__ hist,
                                               int* __restrict__ bsum) {
  __shared__ int red[4];
  int i = blockIdx.x * 256 + threadIdx.x;
  int v = (i < NN) ? hist[i] : 0;
#pragma unroll
  for (int m = 1; m < 64; m <<= 1) v += __shfl_xor(v, m);
  if ((threadIdx.x & 63) == 0) red[threadIdx.x >> 6] = v;
  __syncthreads();
  if (threadIdx.x == 0) bsum[blockIdx.x] = red[0] + red[1] + red[2] + red[3];
}

// each block: scan the 196 block sums locally (L2-hot) + local 256-scan
__global__ __launch_bounds__(256) void k_scan13(const int* __restrict__ hist,
    const int* __restrict__ bsum, int* __restrict__ rowptr,
    int* __restrict__ cursor) {
  __shared__ int s[256];
  int t = threadIdx.x;
  int bv = (t < NBLK) ? bsum[t] : 0;
  s[t] = bv;
  __syncthreads();
  for (int off = 1; off < 256; off <<= 1) {
    int u = (t >= off) ? s[t - off] : 0;
    __syncthreads();
    s[t] += u;
    __syncthreads();
  }
  int bexc = (blockIdx.x == 0) ? 0 : s[blockIdx.x - 1];  // uniform
  __syncthreads();
  int i = blockIdx.x * 256 + t;
  int v = (i < NN) ? hist[i] : 0;
  s[t] = v;
  __syncthreads();
  for (int off = 1; off < 256; off <<= 1) {
    int u = (t >= off) ? s[t - off] : 0;
    __syncthreads();
    s[t] += u;
    __syncthreads();
  }
  int excl = bexc + s[t] - v;
  if (i < NN) { rowptr[i] = excl; cursor[i] = excl; }  // cursor aliases hist: block-local RAW, safe
  if (i == 0) rowptr[NN] = NE;   // all edges binned (dst clamped)
}

// scatter pre-packed (src<<3 | et) into dst-sorted order (int32 side arrays)
__global__ __launch_bounds__(256) void k_scatter(const int* __restrict__ dstp,
    const int* __restrict__ setp, int* __restrict__ cursor,
    int* __restrict__ srcet) {
  int e = blockIdx.x * 256 + threadIdx.x;   // HBLK*256 == NE
  int dst = dstp[e];
  int pos = atomicAdd(&cursor[dst], 1);
  srcet[pos] = setp[e];
}

// ---- fused attention+gather: 1 wave/node, 2 channels/lane, unroll-4 ---------
// lane l: head h = l>>4, channel pair j0 = 32h + 2*(l&15), j0+1
__global__ __launch_bounds__(256) void k_gather(const int* __restrict__ rowptr,
    const int* __restrict__ srcet, const unsigned short* __restrict__ qb,
    const unsigned* __restrict__ kvb, const float* __restrict__ ee,
    const int* __restrict__ flag, void* __restrict__ out) {
  int n = blockIdx.x * 4 + (threadIdx.x >> 6);   // wave-uniform node
  int l = threadIdx.x & 63;
  int j0 = ((l >> 4) << 5) + ((l & 15) << 1);    // channel pair base
  int beg = __builtin_amdgcn_readfirstlane(rowptr[n]);
  int end = __builtin_amdgcn_readfirstlane(rowptr[n + 1]);
  unsigned qp = *(const unsigned*)(qb + (size_t)n * HC + j0);
  float q0 = bflo(qp), q1 = bfhi(qp);
  const float sc = 0.17677669529663687f;  // 1/sqrt(32)
  float dn = 0.f, a0 = 0.f, a1 = 0.f;
  int p = beg;
  for (; p + 4 <= end; p += 4) {
    int se[4];
    uint2 kv[4];
    float2 ev[4];
#pragma unroll
    for (int t = 0; t < 4; ++t) se[t] = srcet[p + t];         // s_load_dwordx4
#pragma unroll
    for (int t = 0; t < 4; ++t)
      kv[t] = *(const uint2*)(kvb + (size_t)(se[t] >> 3) * HC + j0);
#pragma unroll
    for (int t = 0; t < 4; ++t)
      ev[t] = *(const float2*)(ee + ((se[t] & 7) << 7) + j0);
#pragma unroll
    for (int t = 0; t < 4; ++t) {
      float k0 = bflo(kv[t].x) + ev[t].x;
      float k1 = bflo(kv[t].y) + ev[t].y;
      float pp = q0 * k0 + q1 * k1;
      pp += __shfl_xor(pp, 1);
      pp += __shfl_xor(pp, 2);
      pp += __shfl_xor(pp, 4);
      pp += __shfl_xor(pp, 8);
      float xx = __expf(pp * sc);
      dn += xx;
      a0 += (bfhi(kv[t].x) + ev[t].x) * xx;
      a1 += (bfhi(kv[t].y) + ev[t].y) * xx;
    }
  }
  for (; p < end; ++p) {
    int se0 = srcet[p];
    uint2 kv0 = *(const uint2*)(kvb + (size_t)(se0 >> 3) * HC + j0);
    float2 ev0 = *(const float2*)(ee + ((se0 & 7) << 7) + j0);
    float k0 = bflo(kv0.x) + ev0.x;
    float k1 = bflo(kv0.y) + ev0.y;
    float pp = q0 * k0 + q1 * k1;
    pp += __shfl_xor(pp, 1);
    pp += __shfl_xor(pp, 2);
    pp += __shfl_xor(pp, 4);
    pp += __shfl_xor(pp, 8);
    float xx = __expf(pp * sc);
    dn += xx;
    a0 += (bfhi(kv0.x) + ev0.x) * xx;
    a1 += (bfhi(kv0.y) + ev0.y) * xx;
  }
  float inv = 1.f / (dn + 1e-16f);
  float o0 = a0 * inv, o1 = a1 * inv;
  size_t oi = (size_t)n * HC + j0;
  if (flag[1]) {  // skip was stored dtype-matched in d_out; same-thread RAW, safe
    unsigned sk = *(const unsigned*)((const unsigned short*)out + oi);
    o0 += bflo(sk);
    o1 += bfhi(sk);
    *(unsigned*)((unsigned short*)out + oi) = pack2bf(o0, o1);
  } else {
    float2 sk = *(const float2*)((const float*)out + oi);
    float2 ov = make_float2(o0 + sk.x, o1 + sk.y);
    *(float2*)((float*)out + oi) = ov;
  }
}

// ---- launch -----------------------------------------------------------------
extern "C" void kernel_launch(void* const* d_in, const int* in_sizes, int n_in,
                              void* d_out, int out_size, void* d_ws, size_t ws_size,
                              hipStream_t stream) {
  const void* x     = d_in[0];
  const void* eidx  = d_in[1];   // [2,E]: first E = src, next E = dst
  const void* etype = d_in[2];
  const void* emb   = d_in[3];
  const void* Wq    = d_in[4];
  const void* Wk    = d_in[5];
  const void* Wv    = d_in[6];
  const void* We    = d_in[7];
  const void* Ws    = d_in[8];

  // workspace layout (float units) — total ~48.4 MB (round-3/4 proven-safe)
  float* base   = (float*)d_ws;
  int*   flag   = (int*)base;                       // 16
  float* ee     = base + 16;                        // 1024 -> 1040
  int*   rowptr = (int*)(base + 1040);              // 50001 -> pad 50004
  int*   cursor = (int*)(base + 51044);             // 50000 (doubles as hist)
  int*   bsum   = (int*)(base + 101044);            // 196 -> pad 524
  int*   srcet  = (int*)(base + 101568);            // NE -> 901568
  int*   dstp   = (int*)(base + 901568);            // NE -> 1701568
  int*   setp   = (int*)(base + 1701568);           // NE -> 2501568
  unsigned short* qb  = (unsigned short*)(base + 2501568);  // NN*HC bf16 (3.2M fl)
  unsigned*       kvb = (unsigned*)(base + 5701568);        // NN*HC uint (6.4M fl)
  // end: 12101568 floats = 48.41 MB

  hipMemsetAsync(cursor, 0, NN * sizeof(int), stream);   // hist zero (capture-safe)
  k_prep   <<<HBLK + 1, 256, 0, stream>>>((const int*)eidx, etype,
                                          (const unsigned*)x, emb, We,
                                          flag, cursor, ee, dstp, setp);
  k_qkvs   <<<2 * QBLK, 256, 0, stream>>>(x, Wq, Wk, Wv, Ws, flag, qb, kvb, d_out);
  k_scan1  <<<NBLK, 256, 0, stream>>>(cursor, bsum);
  k_scan13 <<<NBLK, 256, 0, stream>>>(cursor, bsum, rowptr, cursor);
  k_scatter<<<HBLK, 256, 0, stream>>>(dstp, setp, cursor, srcet);
  k_gather <<<NN / 4, 256, 0, stream>>>(rowptr, srcet, qb, kvb, ee, flag, d_out);
}

// Round 9
// 284.598 us; speedup vs baseline: 20.2073x; 1.0372x over previous
//
#include <hip/hip_runtime.h>
#include <hip/hip_bf16.h>

// Problem constants (from reference):
#define NN 50000   // nodes
#define FF 128     // in channels
#define NH 4       // heads
#define CH 32      // channels/head
#define HC 128     // NH*CH
#define NE 800000  // edges
#define NR 8       // relations
#define DEDIM 64   // edge emb dim
#define NBLK 196   // ceil(NN/256)
#define HBLK 3125  // NE/256
#define QBLK 250   // M-chunk blocks per group in qkvs
#define MTILES 3125 // NN/16

typedef __hip_bfloat16 bf16;
typedef __attribute__((ext_vector_type(8))) short short8;   // 8 x bf16 (4 VGPR)
typedef __attribute__((ext_vector_type(4))) float f32x4;

// ---- helpers ----------------------------------------------------------------
__device__ __forceinline__ float bflo(unsigned u) { return __uint_as_float(u << 16); }
__device__ __forceinline__ float bfhi(unsigned u) { return __uint_as_float(u & 0xFFFF0000u); }

__device__ __forceinline__ unsigned short f2bf(float f) {
  unsigned u = __float_as_uint(f);
  unsigned r = (u + 0x7FFFu + ((u >> 16) & 1u)) >> 16;  // round-nearest-even
  return (unsigned short)r;
}
__device__ __forceinline__ unsigned pack2bf(float lo, float hi) {
  return (unsigned)f2bf(lo) | ((unsigned)f2bf(hi) << 16);
}

template <int ISBF>
__device__ __forceinline__ float ldf(const void* p, size_t i) {
  if (ISBF) return __bfloat162float(((const bf16*)p)[i]);
  return ((const float*)p)[i];
}

__device__ __forceinline__ int idx_at(const void* p, long long i, int is64) {
  if (is64) { long long v = ((const long long*)p)[i]; return (int)v; }
  return ((const int*)p)[i];
}

// ---- MFMA projection pieces --------------------------------------------------
#define WT_STRIDE 136   // bf16 elems; 272 B rows: 16B-aligned, 2-way max bank alias

template <int ISBF>
__device__ __forceinline__ void stage_w(const void* __restrict__ W,
                                        unsigned short* __restrict__ wt) {
  for (int i = threadIdx.x; i < FF * HC; i += 256) {
    int k = i >> 7, n = i & 127;
    wt[n * WT_STRIDE + k] = ISBF ? ((const unsigned short*)W)[i]
                                 : f2bf(((const float*)W)[i]);
  }
}

__device__ __forceinline__ void hoist_b(const unsigned short* __restrict__ wt,
                                        int wv, int quad, int lr,
                                        short8 bf[2][4]) {
#pragma unroll
  for (int t = 0; t < 2; ++t) {
    int ncol = wv * 32 + t * 16 + lr;
#pragma unroll
    for (int kb = 0; kb < 4; ++kb)
      bf[t][kb] = *(const short8*)&wt[ncol * WT_STRIDE + kb * 32 + quad * 8];
  }
}

template <int ISBF>
__device__ __forceinline__ void qkvs_body(const void* __restrict__ x,
    const void* __restrict__ W0, const void* __restrict__ W1, int grp, int mc,
    unsigned short* __restrict__ qb, unsigned* __restrict__ kvb,
    void* __restrict__ out, unsigned short* wt) {
  const int lane = threadIdx.x & 63;
  const int wv   = threadIdx.x >> 6;
  const int quad = lane >> 4;
  const int lr   = lane & 15;
  short8 bf0[2][4], bf1[2][4];
  stage_w<ISBF>(W0, wt);
  __syncthreads();
  hoist_b(wt, wv, quad, lr, bf0);
  __syncthreads();           // all reads of W0 done before overwrite
  stage_w<ISBF>(W1, wt);
  __syncthreads();
  hoist_b(wt, wv, quad, lr, bf1);
  const unsigned short* xu = (const unsigned short*)x;
  const float* xf = (const float*)x;
  for (int mt = mc; mt < MTILES; mt += QBLK) {
    int m0 = mt * 16;
    short8 af[4];
#pragma unroll
    for (int kb = 0; kb < 4; ++kb) {
      size_t off = (size_t)(m0 + lr) * FF + kb * 32 + quad * 8;
      if (ISBF) {
        af[kb] = *(const short8*)(xu + off);
      } else {
        float4 fa = *(const float4*)(xf + off);
        float4 fb = *(const float4*)(xf + off + 4);
        short8 a;
        a[0] = (short)f2bf(fa.x); a[1] = (short)f2bf(fa.y);
        a[2] = (short)f2bf(fa.z); a[3] = (short)f2bf(fa.w);
        a[4] = (short)f2bf(fb.x); a[5] = (short)f2bf(fb.y);
        a[6] = (short)f2bf(fb.z); a[7] = (short)f2bf(fb.w);
        af[kb] = a;
      }
    }
    f32x4 a00 = {0.f, 0.f, 0.f, 0.f}, a01 = {0.f, 0.f, 0.f, 0.f};
    f32x4 a10 = {0.f, 0.f, 0.f, 0.f}, a11 = {0.f, 0.f, 0.f, 0.f};
#pragma unroll
    for (int kb = 0; kb < 4; ++kb) {
      a00 = __builtin_amdgcn_mfma_f32_16x16x32_bf16(af[kb], bf0[0][kb], a00, 0, 0, 0);
      a01 = __builtin_amdgcn_mfma_f32_16x16x32_bf16(af[kb], bf0[1][kb], a01, 0, 0, 0);
      a10 = __builtin_amdgcn_mfma_f32_16x16x32_bf16(af[kb], bf1[0][kb], a10, 0, 0, 0);
      a11 = __builtin_amdgcn_mfma_f32_16x16x32_bf16(af[kb], bf1[1][kb], a11, 0, 0, 0);
    }
#pragma unroll
    for (int t = 0; t < 2; ++t) {
      const f32x4 v0 = t ? a01 : a00;   // mat0: q or k
      const f32x4 v1 = t ? a11 : a10;   // mat1: skip or v
      int col = wv * 32 + t * 16 + lr;
#pragma unroll
      for (int r = 0; r < 4; ++r) {
        size_t oi = (size_t)(m0 + quad * 4 + r) * HC + col;
        if (grp == 0) {
          qb[oi] = f2bf(v0[r]);
          if (ISBF) ((unsigned short*)out)[oi] = f2bf(v1[r]);
          else      ((float*)out)[oi] = v1[r];
        } else {
          kvb[oi] = pack2bf(v0[r], v1[r]);   // k low16, v high16
        }
      }
    }
  }
}

// ---- fused prep + qkvs + detect/ee ------------------------------------------
// blocks [0,HBLK): edge prep (hist/dstp/setp, self-detect is64)
// blocks [HBLK, HBLK+2*QBLK): MFMA projections (self-detect bf16)
// block HBLK+2*QBLK: flag store + ee
// hist pre-zeroed via hipMemsetAsync.
__global__ __launch_bounds__(256) void k_prepx(const int* __restrict__ eidx32,
    const void* __restrict__ etype, const unsigned* __restrict__ xw,
    const void* __restrict__ emb, const void* __restrict__ We,
    const void* __restrict__ Wq, const void* __restrict__ Wk,
    const void* __restrict__ Wv, const void* __restrict__ Ws,
    int* __restrict__ flag, int* __restrict__ hist, float* __restrict__ ee,
    int* __restrict__ dstp, int* __restrict__ setp,
    unsigned short* __restrict__ qb, unsigned* __restrict__ kvb,
    void* __restrict__ out) {
  __shared__ unsigned short wt[HC * WT_STRIDE];   // ~34 KB (aliased below)
  if (blockIdx.x < HBLK) {
    // wave-local int64 detection: 64 distinct hi-word samples
    unsigned long long b = __ballot(eidx32[2 * (threadIdx.x & 63) + 1] != 0);
    int is64 = (b == 0ULL);
    int e = blockIdx.x * 256 + threadIdx.x;   // always < NE (HBLK*256 == NE)
    int src = idx_at(eidx32, e, is64);
    int dst = idx_at(eidx32, (long long)NE + e, is64);
    int et  = idx_at(etype, e, is64);
    src = min(max(src, 0), NN - 1);
    dst = min(max(dst, 0), NN - 1);
    et  = min(max(et, 0), NR - 1);
    dstp[e] = dst;
    setp[e] = (src << 3) | et;
    atomicAdd(&hist[dst], 1);
    return;
  }
  if (blockIdx.x < HBLK + 2 * QBLK) {
    // wave-local bf16 detection: 64 exponent samples of x's low halves
    unsigned ex = (xw[threadIdx.x & 63] >> 7) & 0xFFu;
    unsigned long long bb = __ballot(ex < 90u || ex > 140u);
    int isbf = (bb == 0ULL);
    int b2  = blockIdx.x - HBLK;
    int grp = b2 / QBLK;   // 0: q+skip, 1: k+v
    int mc  = b2 % QBLK;
    const void* W0 = grp ? Wk : Wq;
    const void* W1 = grp ? Wv : Ws;
    if (isbf) qkvs_body<1>(xw, W0, W1, grp, mc, qb, kvb, out, wt);
    else      qkvs_body<0>(xw, W0, W1, grp, mc, qb, kvb, out, wt);
    return;
  }
  // last block: flags + ee
  float* es = (float*)wt;   // alias (this block doesn't run qkvs)
  __shared__ int nzIdx, badBf;
  if (threadIdx.x == 0) { nzIdx = 0; badBf = 0; }
  __syncthreads();
  if (threadIdx.x < 128) {
    if (eidx32[2 * threadIdx.x + 1] != 0) atomicAdd(&nzIdx, 1);
    unsigned e = (xw[threadIdx.x] >> 7) & 0xFFu;
    if (e < 90u || e > 140u) atomicAdd(&badBf, 1);
  }
  __syncthreads();
  const int isbf = (badBf == 0);
  if (threadIdx.x == 0) { flag[0] = (nzIdx == 0); flag[1] = isbf; }
  for (int i = threadIdx.x; i < NR * DEDIM; i += 256)
    es[i] = isbf ? ldf<1>(emb, i) : ldf<0>(emb, i);
  __syncthreads();
  for (int o = threadIdx.x; o < NR * HC; o += 256) {
    int r = o >> 7, j = o & 127;
    float acc = 0.f;
    if (isbf) { for (int d = 0; d < DEDIM; ++d) acc += es[r * DEDIM + d] * ldf<1>(We, d * HC + j); }
    else      { for (int d = 0; d < DEDIM; ++d) acc += es[r * DEDIM + d] * ldf<0>(We, d * HC + j); }
    ee[o] = acc;
  }
}

// ---- scan: block sums (scan1), then per-block scan with inline top scan ------
__global__ __launch_bounds__(256) void k_scan1(const int* __restrict__ hist,
                                               int* __restrict__ bsum) {
  __shared__ int red[4];
  int i = blockIdx.x * 256 + threadIdx.x;
  int v = (i < NN) ? hist[i] : 0;
#pragma unroll
  for (int m = 1; m < 64; m <<= 1) v += __shfl_xor(v, m);
  if ((threadIdx.x & 63) == 0) red[threadIdx.x >> 6] = v;
  __syncthreads();
  if (threadIdx.x == 0) bsum[blockIdx.x] = red[0] + red[1] + red[2] + red[3];
}

__global__ __launch_bounds__(256) void k_scan13(const int* __restrict__ hist,
    const int* __restrict__ bsum, int* __restrict__ rowptr,
    int* __restrict__ cursor) {
  __shared__ int s[256];
  int t = threadIdx.x;
  int bv = (t < NBLK) ? bsum[t] : 0;
  s[t] = bv;
  __syncthreads();
  for (int off = 1; off < 256; off <<= 1) {
    int u = (t >= off) ? s[t - off] : 0;
    __syncthreads();
    s[t] += u;
    __syncthreads();
  }
  int bexc = (blockIdx.x == 0) ? 0 : s[blockIdx.x - 1];  // uniform
  __syncthreads();
  int i = blockIdx.x * 256 + t;
  int v = (i < NN) ? hist[i] : 0;
  s[t] = v;
  __syncthreads();
  for (int off = 1; off < 256; off <<= 1) {
    int u = (t >= off) ? s[t - off] : 0;
    __syncthreads();
    s[t] += u;
    __syncthreads();
  }
  int excl = bexc + s[t] - v;
  if (i < NN) { rowptr[i] = excl; cursor[i] = excl; }  // cursor aliases hist: block-local RAW, safe
  if (i == 0) rowptr[NN] = NE;   // all edges binned (dst clamped)
}

// scatter pre-packed (src<<3 | et) into dst-sorted order (int32 side arrays)
__global__ __launch_bounds__(256) void k_scatter(const int* __restrict__ dstp,
    const int* __restrict__ setp, int* __restrict__ cursor,
    int* __restrict__ srcet) {
  int e = blockIdx.x * 256 + threadIdx.x;   // HBLK*256 == NE
  int dst = dstp[e];
  int pos = atomicAdd(&cursor[dst], 1);
  srcet[pos] = setp[e];
}

// ---- fused attention+gather: half-wave per edge, 4 channels/lane ------------
// lane l: t = l>>5 (edge slot), w = l&31, head = w>>3, j0 = 32*head + 4*(w&7)
__global__ __launch_bounds__(256) void k_gather(const int* __restrict__ rowptr,
    const int* __restrict__ srcet, const unsigned short* __restrict__ qb,
    const unsigned* __restrict__ kvb, const float* __restrict__ ee,
    const int* __restrict__ flag, void* __restrict__ out) {
  int n = blockIdx.x * 4 + (threadIdx.x >> 6);   // wave-uniform node
  int l = threadIdx.x & 63;
  int t = l >> 5;
  int w = l & 31;
  int j0 = ((w >> 3) << 5) + ((w & 7) << 2);     // 4-channel base
  int beg = __builtin_amdgcn_readfirstlane(rowptr[n]);
  int end = __builtin_amdgcn_readfirstlane(rowptr[n + 1]);
  uint2 qw = *(const uint2*)(qb + (size_t)n * HC + j0);
  float q0 = bflo(qw.x), q1 = bfhi(qw.x), q2 = bflo(qw.y), q3 = bfhi(qw.y);
  const float sc = 0.17677669529663687f;  // 1/sqrt(32)
  float dn = 0.f, a0 = 0.f, a1 = 0.f, a2 = 0.f, a3 = 0.f;
  int p = beg;
  // main: 4 pairs (8 edges) per iteration, unmasked
  for (; p + 8 <= end; p += 8) {
    int se[4]; uint4 kv[4]; float4 ev[4];
#pragma unroll
    for (int u = 0; u < 4; ++u) se[u] = srcet[p + 2 * u + t];
#pragma unroll
    for (int u = 0; u < 4; ++u)
      kv[u] = *(const uint4*)(kvb + (size_t)(se[u] >> 3) * HC + j0);
#pragma unroll
    for (int u = 0; u < 4; ++u)
      ev[u] = *(const float4*)(ee + ((se[u] & 7) << 7) + j0);
#pragma unroll
    for (int u = 0; u < 4; ++u) {
      float pp = q0 * (bflo(kv[u].x) + ev[u].x) + q1 * (bflo(kv[u].y) + ev[u].y)
               + q2 * (bflo(kv[u].z) + ev[u].z) + q3 * (bflo(kv[u].w) + ev[u].w);
      pp += __shfl_xor(pp, 1);
      pp += __shfl_xor(pp, 2);
      pp += __shfl_xor(pp, 4);
      float xx = __expf(pp * sc);
      dn += xx;
      a0 += (bfhi(kv[u].x) + ev[u].x) * xx;
      a1 += (bfhi(kv[u].y) + ev[u].y) * xx;
      a2 += (bfhi(kv[u].z) + ev[u].z) * xx;
      a3 += (bfhi(kv[u].w) + ev[u].w) * xx;
    }
  }
  // epilogue: one masked 4-pair iteration covers the <8 remaining edges
  if (p < end) {
    int se[4]; bool ok[4]; uint4 kv[4]; float4 ev[4];
#pragma unroll
    for (int u = 0; u < 4; ++u) {
      int pe = p + 2 * u + t;
      ok[u] = pe < end;
      se[u] = srcet[ok[u] ? pe : beg];
    }
#pragma unroll
    for (int u = 0; u < 4; ++u)
      kv[u] = *(const uint4*)(kvb + (size_t)(se[u] >> 3) * HC + j0);
#pragma unroll
    for (int u = 0; u < 4; ++u)
      ev[u] = *(const float4*)(ee + ((se[u] & 7) << 7) + j0);
#pragma unroll
    for (int u = 0; u < 4; ++u) {
      float pp = q0 * (bflo(kv[u].x) + ev[u].x) + q1 * (bflo(kv[u].y) + ev[u].y)
               + q2 * (bflo(kv[u].z) + ev[u].z) + q3 * (bflo(kv[u].w) + ev[u].w);
      pp += __shfl_xor(pp, 1);
      pp += __shfl_xor(pp, 2);
      pp += __shfl_xor(pp, 4);
      float xx = ok[u] ? __expf(pp * sc) : 0.f;
      dn += xx;
      a0 += (bfhi(kv[u].x) + ev[u].x) * xx;
      a1 += (bfhi(kv[u].y) + ev[u].y) * xx;
      a2 += (bfhi(kv[u].z) + ev[u].z) * xx;
      a3 += (bfhi(kv[u].w) + ev[u].w) * xx;
    }
  }
  // combine the two half-waves (linear in numerator and denominator)
  dn += __shfl_xor(dn, 32);
  a0 += __shfl_xor(a0, 32);
  a1 += __shfl_xor(a1, 32);
  a2 += __shfl_xor(a2, 32);
  a3 += __shfl_xor(a3, 32);
  if (t == 0) {
    float inv = 1.f / (dn + 1e-16f);
    size_t oi = (size_t)n * HC + j0;
    if (flag[1]) {  // skip pre-stored dtype-matched in d_out; same-thread RAW, safe
      uint2 sk = *(const uint2*)((const unsigned short*)out + oi);
      uint2 o;
      o.x = pack2bf(a0 * inv + bflo(sk.x), a1 * inv + bfhi(sk.x));
      o.y = pack2bf(a2 * inv + bflo(sk.y), a3 * inv + bfhi(sk.y));
      *(uint2*)((unsigned short*)out + oi) = o;
    } else {
      float4 sk = *(const float4*)((const float*)out + oi);
      float4 o = make_float4(a0 * inv + sk.x, a1 * inv + sk.y,
                             a2 * inv + sk.z, a3 * inv + sk.w);
      *(float4*)((float*)out + oi) = o;
    }
  }
}

// ---- launch -----------------------------------------------------------------
extern "C" void kernel_launch(void* const* d_in, const int* in_sizes, int n_in,
                              void* d_out, int out_size, void* d_ws, size_t ws_size,
                              hipStream_t stream) {
  const void* x     = d_in[0];
  const void* eidx  = d_in[1];   // [2,E]: first E = src, next E = dst
  const void* etype = d_in[2];
  const void* emb   = d_in[3];
  const void* Wq    = d_in[4];
  const void* Wk    = d_in[5];
  const void* Wv    = d_in[6];
  const void* We    = d_in[7];
  const void* Ws    = d_in[8];

  // workspace layout (float units) — total ~48.4 MB (round-3/4 proven-safe)
  float* base   = (float*)d_ws;
  int*   flag   = (int*)base;                       // 16
  float* ee     = base + 16;                        // 1024 -> 1040
  int*   rowptr = (int*)(base + 1040);              // 50001 -> pad 50004
  int*   cursor = (int*)(base + 51044);             // 50000 (doubles as hist)
  int*   bsum   = (int*)(base + 101044);            // 196 -> pad 524
  int*   srcet  = (int*)(base + 101568);            // NE -> 901568
  int*   dstp   = (int*)(base + 901568);            // NE -> 1701568
  int*   setp   = (int*)(base + 1701568);           // NE -> 2501568
  unsigned short* qb  = (unsigned short*)(base + 2501568);  // NN*HC bf16 (3.2M fl)
  unsigned*       kvb = (unsigned*)(base + 5701568);        // NN*HC uint (6.4M fl)
  // end: 12101568 floats = 48.41 MB

  hipMemsetAsync(cursor, 0, NN * sizeof(int), stream);   // hist zero (capture-safe)
  k_prepx  <<<HBLK + 2 * QBLK + 1, 256, 0, stream>>>((const int*)eidx, etype,
                                          (const unsigned*)x, emb, We,
                                          Wq, Wk, Wv, Ws,
                                          flag, cursor, ee, dstp, setp,
                                          qb, kvb, d_out);
  k_scan1  <<<NBLK, 256, 0, stream>>>(cursor, bsum);
  k_scan13 <<<NBLK, 256, 0, stream>>>(cursor, bsum, rowptr, cursor);
  k_scatter<<<HBLK, 256, 0, stream>>>(dstp, setp, cursor, srcet);
  k_gather <<<NN / 4, 256, 0, stream>>>(rowptr, srcet, qb, kvb, ee, flag, d_out);
}